// Round 12
// baseline (717.422 us; speedup 1.0000x reference)
//
#include <hip/hip_runtime.h>
#include <hip/hip_bf16.h>
#include <math.h>

typedef __hip_bfloat16 bf16;
typedef __attribute__((ext_vector_type(8))) short short8;   // 8 bf16 = 4 VGPR
typedef __attribute__((ext_vector_type(4))) short short4v;  // 4 bf16
typedef __attribute__((ext_vector_type(4))) float f32x4;

#define C1F 0.18033688011112042f  // 0.125 * log2(e)
#define LOG2E 1.44269504088896f

__device__ __forceinline__ float to_f(float x) { return x; }
__device__ __forceinline__ float to_f(bf16 x) { return __bfloat162float(x); }

template <typename T> __device__ __forceinline__ T from_f(float x);
template <> __device__ __forceinline__ float from_f<float>(float x) { return x; }
template <> __device__ __forceinline__ bf16 from_f<bf16>(float x) { return __float2bfloat16(x); }

__device__ __forceinline__ float gelu_exact(float x) {
    return 0.5f * x * (1.0f + erff(x * 0.70710678118654752f));
}

#define GLD_LDS16(g, l)                                               \
    __builtin_amdgcn_global_load_lds(                                 \
        (const __attribute__((address_space(1))) void*)(g),           \
        (__attribute__((address_space(3))) void*)(l), 16, 0, 0)

// ---------------------------------------------------------------------------
// Fold Q/K/V low-rank weights via LDS staging. Q weights pre-scaled by C1
// (0.125*log2e) so attention's softmax needs no per-score multiply.
// ---------------------------------------------------------------------------
__global__ __launch_bounds__(256) void build_w_qkv_lds(const float* __restrict__ Pq,
                                                       const float* __restrict__ Vq,
                                                       const float* __restrict__ Pk,
                                                       const float* __restrict__ Vk,
                                                       const float* __restrict__ Pv,
                                                       const float* __restrict__ Vv,
                                                       bf16* __restrict__ Wt) {
    const int dt = blockIdx.x;     // 0..5
    const int h = blockIdx.y;      // 0..11
    const int which = blockIdx.z;  // 0..2
    const float* P = (which == 0) ? Pq : (which == 1) ? Pk : Pv;
    const float* V = (which == 0) ? Vq : (which == 1) ? Vk : Vv;
    const float scale = (which == 0) ? C1F : 1.0f;
    __shared__ __align__(16) float Ps[128][36];
    __shared__ __align__(16) float Vs[32][64];
    __shared__ __align__(16) unsigned int Ot[64][68];
    const int tid = threadIdx.x;

    const float* pbase = P + ((size_t)h * 768 + dt * 128) * 32;
#pragma unroll
    for (int i = 0; i < 4; i++) {
        int idx = tid + i * 256;
        float4 v4 = ((const float4*)pbase)[idx];
        *(float4*)&Ps[idx >> 3][(idx & 7) * 4] = v4;
    }
    const float* vbase = V + (size_t)h * 2048;
#pragma unroll
    for (int i = 0; i < 2; i++) {
        int idx = tid + i * 256;
        ((float4*)&Vs[0][0])[idx] = ((const float4*)vbase)[idx];
    }
    __syncthreads();

    const int e = tid & 63, w = tid >> 6;
    float vreg[32];
#pragma unroll
    for (int r = 0; r < 32; r++) vreg[r] = Vs[r][e];

#pragma unroll
    for (int dp = 0; dp < 16; dp++) {
        const int d0 = w * 32 + dp * 2;
        float a0 = 0.f, a1 = 0.f;
#pragma unroll
        for (int r4 = 0; r4 < 8; r4++) {
            float4 p0 = *(const float4*)&Ps[d0][r4 * 4];
            float4 p1 = *(const float4*)&Ps[d0 + 1][r4 * 4];
            a0 += p0.x * vreg[r4 * 4] + p0.y * vreg[r4 * 4 + 1] + p0.z * vreg[r4 * 4 + 2] + p0.w * vreg[r4 * 4 + 3];
            a1 += p1.x * vreg[r4 * 4] + p1.y * vreg[r4 * 4 + 1] + p1.z * vreg[r4 * 4 + 2] + p1.w * vreg[r4 * 4 + 3];
        }
        a0 *= scale;
        a1 *= scale;
        unsigned int lo = (unsigned int)(unsigned short)__builtin_bit_cast(short, from_f<bf16>(a0));
        unsigned int hi = (unsigned int)(unsigned short)__builtin_bit_cast(short, from_f<bf16>(a1));
        Ot[e][w * 16 + dp] = lo | (hi << 16);
    }
    __syncthreads();

    const int erow = tid >> 2, c0 = (tid & 3) * 16;
    bf16* dst = Wt + ((size_t)which * 768 + h * 64 + erow) * 768 + dt * 128 + c0 * 2;
    *(uint4*)(dst) = *(const uint4*)&Ot[erow][c0];
    *(uint4*)(dst + 8) = *(const uint4*)&Ot[erow][c0 + 4];
    *(uint4*)(dst + 16) = *(const uint4*)&Ot[erow][c0 + 8];
    *(uint4*)(dst + 24) = *(const uint4*)&Ot[erow][c0 + 12];
}

// ---------------------------------------------------------------------------
// LDS-tiled cast-transpose: in [R][Cc] f32 -> out [Cc][R] bf16. 32x32 tiles.
// ---------------------------------------------------------------------------
__device__ __forceinline__ void ct_tile(const float* in, bf16* out, int R, int Cc,
                                        int r0, int c0, int tx, int ty) {
    __shared__ float t[32][33];
#pragma unroll
    for (int i = 0; i < 4; i++)
        t[ty + i * 8][tx] = in[(size_t)(r0 + ty + i * 8) * Cc + c0 + tx];
    __syncthreads();
#pragma unroll
    for (int i = 0; i < 4; i++)
        out[(size_t)(c0 + ty + i * 8) * R + r0 + tx] = from_f<bf16>(t[tx][ty + i * 8]);
}

// Batched: U1(768x256), V1(256x3072), U2(3072x256), V2(256x768), Vo(256x768).
__global__ __launch_bounds__(256) void cast_transpose_batch(const float* __restrict__ U1,
                                                            const float* __restrict__ V1,
                                                            const float* __restrict__ U2,
                                                            const float* __restrict__ V2,
                                                            const float* __restrict__ Vo,
                                                            bf16* __restrict__ U1t,
                                                            bf16* __restrict__ V1t,
                                                            bf16* __restrict__ U2t,
                                                            bf16* __restrict__ V2t,
                                                            bf16* __restrict__ Vot) {
    int t = blockIdx.x;
    const float* in;
    bf16* out;
    int R, Cc;
    if (t < 192) { in = U1; out = U1t; R = 768; Cc = 256; }
    else if (t < 960) { t -= 192; in = V1; out = V1t; R = 256; Cc = 3072; }
    else if (t < 1728) { t -= 960; in = U2; out = U2t; R = 3072; Cc = 256; }
    else if (t < 1920) { t -= 1728; in = V2; out = V2t; R = 256; Cc = 768; }
    else { t -= 1920; in = Vo; out = Vot; R = 256; Cc = 768; }
    const int tpr = Cc >> 5;
    ct_tile(in, out, R, Cc, (t / tpr) * 32, (t % tpr) * 32,
            threadIdx.x & 31, threadIdx.x >> 5);
}

// dual cast: x (n4a float4s) then Uo (n4b float4s)
__global__ __launch_bounds__(256) void cast_f32_bf16_dual(const float* __restrict__ a,
                                                          bf16* __restrict__ oa, int n4a,
                                                          const float* __restrict__ bsrc,
                                                          bf16* __restrict__ ob, int n4b) {
    int t = blockIdx.x * 256 + threadIdx.x;
    const float* in;
    bf16* out;
    int i;
    if (t < n4a) { in = a; out = oa; i = t; }
    else if (t < n4a + n4b) { in = bsrc; out = ob; i = t - n4a; }
    else return;
    float4 v = ((const float4*)in)[i];
    bf16 tmp[4] = {from_f<bf16>(v.x), from_f<bf16>(v.y), from_f<bf16>(v.z), from_f<bf16>(v.w)};
    ((short4v*)out)[i] = *(short4v*)tmp;
}

// bias packing (bq pre-scaled by C1) + mask pre-scale (mask2 = mask * log2e)
__global__ __launch_bounds__(256) void pack_bias_mask(const float* __restrict__ bq,
                                                      const float* __restrict__ bk,
                                                      const float* __restrict__ bv,
                                                      const float* __restrict__ mask,
                                                      float* __restrict__ bias_out,
                                                      float* __restrict__ mask2) {
    int t = blockIdx.x * 256 + threadIdx.x;
    if (t < 768) {
        bias_out[t] = bq[t] * C1F;
        bias_out[768 + t] = bk[t];
        bias_out[1536 + t] = bv[t];
    }
    int m = t - 768;
    if (m >= 0 && m < 8192) mask2[m] = mask[m] * LOG2E;
}

// ---------------------------------------------------------------------------
// MFMA GEMM: C[M,N] = A[M,K](bf16,row-major) @ Bt[N,K](bf16,K-major) (+bias)(+GELU)
// 128x128 tile, BK=32, 256 thr = 4 waves (2x2 of 64x64). m97 structure.
// ---------------------------------------------------------------------------
template <typename TOUT, int EPI>
__global__ __launch_bounds__(256) void gemm_mfma(const bf16* __restrict__ A,
                                                 const bf16* __restrict__ Bt,
                                                 const float* __restrict__ bias,
                                                 TOUT* __restrict__ C,
                                                 int M, int N, int K) {
    __shared__ __align__(16) bf16 As[128 * 32];
    __shared__ __align__(16) bf16 Bs[128 * 32];
    const int tid = threadIdx.x;
    const int w = tid >> 6, lane = tid & 63;
    const int l = lane & 15, quad = lane >> 4;
    const int wm = w >> 1, wn = w & 1;
    const int m0 = blockIdx.x * 128, n0 = blockIdx.y * 128;

    const int r_in = lane >> 2;
    const int slot = lane & 3;
    const int rA0 = 2 * w * 16 + r_in, rA1 = rA0 + 16;
    const int q0 = slot ^ ((rA0 >> 1) & 3);
    const int q1 = slot ^ ((rA1 >> 1) & 3);
    const bf16* a0 = A + (size_t)(m0 + rA0) * K + q0 * 8;
    const bf16* a1 = A + (size_t)(m0 + rA1) * K + q1 * 8;
    const bf16* b0 = Bt + (size_t)(n0 + rA0) * K + q0 * 8;
    const bf16* b1 = Bt + (size_t)(n0 + rA1) * K + q1 * 8;
    bf16* lA0 = As + 2 * w * 512;
    bf16* lA1 = lA0 + 512;
    bf16* lB0 = Bs + 2 * w * 512;
    bf16* lB1 = lB0 + 512;

    const int swz = (quad ^ ((l >> 1) & 3)) * 8;
    f32x4 acc[4][4] = {};

    for (int k0 = 0; k0 < K; k0 += 32) {
        GLD_LDS16(a0 + k0, lA0);
        GLD_LDS16(a1 + k0, lA1);
        GLD_LDS16(b0 + k0, lB0);
        GLD_LDS16(b1 + k0, lB1);
        __syncthreads();
        short8 af[4], bfr[4];
#pragma unroll
        for (int mt = 0; mt < 4; mt++)
            af[mt] = *(const short8*)&As[(wm * 64 + mt * 16 + l) * 32 + swz];
#pragma unroll
        for (int nt = 0; nt < 4; nt++)
            bfr[nt] = *(const short8*)&Bs[(wn * 64 + nt * 16 + l) * 32 + swz];
#pragma unroll
        for (int mt = 0; mt < 4; mt++)
#pragma unroll
            for (int nt = 0; nt < 4; nt++)
                acc[mt][nt] = __builtin_amdgcn_mfma_f32_16x16x32_bf16(af[mt], bfr[nt], acc[mt][nt], 0, 0, 0);
        __syncthreads();
    }

    float bs[4];
#pragma unroll
    for (int nt = 0; nt < 4; nt++)
        bs[nt] = bias ? bias[n0 + wn * 64 + nt * 16 + l] : 0.f;
#pragma unroll
    for (int mt = 0; mt < 4; mt++) {
#pragma unroll
        for (int nt = 0; nt < 4; nt++) {
            const int col = n0 + wn * 64 + nt * 16 + l;
#pragma unroll
            for (int r = 0; r < 4; r++) {
                const int row = m0 + wm * 64 + mt * 16 + quad * 4 + r;
                float val = acc[mt][nt][r] + bs[nt];
                if (EPI == 1) val = gelu_exact(val);
                C[(size_t)row * N + col] = from_f<TOUT>(val);
            }
        }
    }
}

// ---------------------------------------------------------------------------
// 64x64-tile MFMA GEMM for narrow-N problems (N=256).
// ---------------------------------------------------------------------------
template <typename TOUT, int EPI>
__global__ __launch_bounds__(256) void gemm_mfma64(const bf16* __restrict__ A,
                                                   const bf16* __restrict__ Bt,
                                                   const float* __restrict__ bias,
                                                   TOUT* __restrict__ C,
                                                   int M, int N, int K) {
    __shared__ __align__(16) bf16 As[64 * 32];
    __shared__ __align__(16) bf16 Bs[64 * 32];
    const int tid = threadIdx.x;
    const int w = tid >> 6, lane = tid & 63;
    const int l = lane & 15, quad = lane >> 4;
    const int wm = w >> 1, wn = w & 1;
    const int m0 = blockIdx.x * 64, n0 = blockIdx.y * 64;

    const int cid = tid;
    const int srow = cid >> 2, slot = cid & 3;
    const int gq = slot ^ ((srow >> 1) & 3);
    const bf16* ag = A + (size_t)(m0 + srow) * K + gq * 8;
    const bf16* bg = Bt + (size_t)(n0 + srow) * K + gq * 8;
    bf16* lA = As + w * 512;
    bf16* lB = Bs + w * 512;

    f32x4 acc[2][2] = {};

    for (int k0 = 0; k0 < K; k0 += 32) {
        GLD_LDS16(ag + k0, lA);
        GLD_LDS16(bg + k0, lB);
        __syncthreads();
        short8 af[2], bfr[2];
#pragma unroll
        for (int mt = 0; mt < 2; mt++) {
            const int row = wm * 32 + mt * 16 + l;
            af[mt] = *(const short8*)&As[row * 32 + (quad ^ ((row >> 1) & 3)) * 8];
        }
#pragma unroll
        for (int nt = 0; nt < 2; nt++) {
            const int row = wn * 32 + nt * 16 + l;
            bfr[nt] = *(const short8*)&Bs[row * 32 + (quad ^ ((row >> 1) & 3)) * 8];
        }
#pragma unroll
        for (int mt = 0; mt < 2; mt++)
#pragma unroll
            for (int nt = 0; nt < 2; nt++)
                acc[mt][nt] = __builtin_amdgcn_mfma_f32_16x16x32_bf16(af[mt], bfr[nt], acc[mt][nt], 0, 0, 0);
        __syncthreads();
    }

#pragma unroll
    for (int mt = 0; mt < 2; mt++) {
#pragma unroll
        for (int nt = 0; nt < 2; nt++) {
            const int col = n0 + wn * 32 + nt * 16 + l;
            const float bsv = bias ? bias[col] : 0.f;
#pragma unroll
            for (int r = 0; r < 4; r++) {
                const int row = m0 + wm * 32 + mt * 16 + quad * 4 + r;
                float val = acc[mt][nt][r] + bsv;
                if (EPI == 1) val = gelu_exact(val);
                C[(size_t)row * N + col] = from_f<TOUT>(val);
            }
        }
    }
}

// ---------------------------------------------------------------------------
// Transpose V per head: qkv [b][m][2304] (V at col 1536+h*64+e) -> vt [b][h][e][m]
// ---------------------------------------------------------------------------
__global__ __launch_bounds__(256) void transpose_v(const bf16* __restrict__ qkv,
                                                   bf16* __restrict__ vt) {
    __shared__ __align__(16) bf16 t[64][72];
    const int m0 = blockIdx.x * 64;
    const int h = blockIdx.y;
    const int tid = threadIdx.x;
    const int r = tid >> 2, c0 = (tid & 3) * 16;
    {
        const size_t g = (size_t)(m0 + r) * 2304 + 1536 + h * 64 + c0;
        *(short8*)&t[r][c0] = *(const short8*)(qkv + g);
        *(short8*)&t[r][c0 + 8] = *(const short8*)(qkv + g + 8);
    }
    __syncthreads();
    const int b = m0 >> 11, mm = m0 & 2047;
    const int e = tid >> 2, mi0 = (tid & 3) * 16;
    bf16 tmp[16];
#pragma unroll
    for (int j = 0; j < 16; j++) tmp[j] = t[mi0 + j][e];
    bf16* dst = vt + (((size_t)b * 12 + h) * 64 + e) * 2048 + mm + mi0;
    *(short8*)dst = *(short8*)&tmp[0];
    *(short8*)(dst + 8) = *(short8*)&tmp[8];
}

// ---------------------------------------------------------------------------
// MFMA flash attention, 16x16x32 S^T, k-split x2, double-buffered staging,
// 512-THREAD BLOCKS (8 waves, 256 q-rows). R10 was dependency-bound at
// 4 waves/SIMD; staging amortized over 8 waves (1 K + 1 V chunk/thread),
// LDS 48KB -> 3 blocks/CU = 24 waves/CU; grid 768 = 3x256 exact residency.
// ---------------------------------------------------------------------------
__global__ __launch_bounds__(512, 6) void flash_attn_mfma(const bf16* __restrict__ qkv,
                                                          const bf16* __restrict__ vt,
                                                          const float* __restrict__ mask2,
                                                          bf16* __restrict__ opart0,
                                                          bf16* __restrict__ opart1,
                                                          float* __restrict__ lpart) {
    const int qt = blockIdx.x, h = blockIdx.y;
    const int b = blockIdx.z >> 1, kh = blockIdx.z & 1;
    const int tid = threadIdx.x;
    const int w = tid >> 6, lane = tid & 63;
    const int l = lane & 15, quad = lane >> 4;

    __shared__ __align__(16) bf16 Ks[2][64 * 64];
    __shared__ __align__(16) bf16 Vs[2][64 * 64];
    __shared__ __align__(16) bf16 Ps[8 * 16 * 64];   // 16 rows/wave

    // Q fragments (B-layout: [k=d][n=q]) for 2 m-tiles (Q pre-scaled by C1)
    short8 qf[2][2];
#pragma unroll
    for (int mt = 0; mt < 2; mt++) {
        const int qrow = qt * 256 + w * 32 + mt * 16 + l;
        const bf16* qp = qkv + ((size_t)b * 2048 + qrow) * 2304 + h * 64 + quad * 8;
        qf[mt][0] = *(const short8*)qp;
        qf[mt][1] = *(const short8*)(qp + 32);
    }

    short8 ones;
#pragma unroll
    for (int i = 0; i < 8; i++) ones[i] = (short)0x3F80;  // bf16 1.0

    f32x4 of[2][4] = {};
    f32x4 lacc[2] = {};
    bf16* Pw = Ps + w * 1024;

    // loop-carried staging pointers: 1 K chunk + 1 V chunk per thread
    const int kc0 = kh * 1024;
    const int srow = tid >> 3, sslot = tid & 7;
    const int sgq = sslot ^ (srow & 7);
    const int ldst = tid * 8;
    const bf16* kg = qkv + ((size_t)b * 2048 + kc0 + srow) * 2304 + 768 + h * 64 + sgq * 8;
    const bf16* vg = vt + (((size_t)b * 12 + h) * 64 + srow) * 2048 + kc0 + sgq * 8;
    const float* mp = mask2 + (size_t)b * 2048 + kc0 + quad * 4;

    auto stage = [&](int buf) {
        GLD_LDS16(kg, &Ks[buf][ldst]);
        GLD_LDS16(vg, &Vs[buf][ldst]);
        kg += 64 * 2304;
        vg += 64;
    };

    int cur = 0;
    stage(0);

#pragma unroll 2
    for (int it = 0; it < 16; it++) {
        __syncthreads();  // buf[cur] staged; all waves done reading buf[cur^1]
        float4 mrow[4];
#pragma unroll
        for (int nt = 0; nt < 4; nt++) mrow[nt] = *(const float4*)(mp + nt * 16);
        mp += 64;
        if (it < 15) stage(cur ^ 1);  // prefetch next tile

        const bf16* Kc = Ks[cur];
        const bf16* Vc = Vs[cur];

        // S^T = K · Q^T + mask (acc seeded with log2e-scaled mask rows)
        f32x4 st[2][4];
#pragma unroll
        for (int nt = 0; nt < 4; nt++) {
            const int rb = (nt * 16 + l) * 64;
            short8 kf0 = *(const short8*)&Kc[rb + ((quad) ^ (l & 7)) * 8];
            short8 kf1 = *(const short8*)&Kc[rb + ((4 + quad) ^ (l & 7)) * 8];
#pragma unroll
            for (int mt = 0; mt < 2; mt++) {
                f32x4 a = {mrow[nt].x, mrow[nt].y, mrow[nt].z, mrow[nt].w};
                a = __builtin_amdgcn_mfma_f32_16x16x32_bf16(kf0, qf[mt][0], a, 0, 0, 0);
                a = __builtin_amdgcn_mfma_f32_16x16x32_bf16(kf1, qf[mt][1], a, 0, 0, 0);
                st[mt][nt] = a;
            }
        }

        // P = exp2(st); pack with v_perm (truncation); per-mt sequential
        // store + A-frag read (same-wave LDS ordering is safe)
        short8 pa[2][2];
#pragma unroll
        for (int mt = 0; mt < 2; mt++) {
#pragma unroll
            for (int nt = 0; nt < 4; nt++) {
                float p0 = exp2f(st[mt][nt][0]);
                float p1 = exp2f(st[mt][nt][1]);
                float p2 = exp2f(st[mt][nt][2]);
                float p3 = exp2f(st[mt][nt][3]);
                unsigned d0 = __builtin_amdgcn_perm(__builtin_bit_cast(unsigned, p1),
                                                    __builtin_bit_cast(unsigned, p0), 0x07060302u);
                unsigned d1 = __builtin_amdgcn_perm(__builtin_bit_cast(unsigned, p3),
                                                    __builtin_bit_cast(unsigned, p2), 0x07060302u);
                const int slot8 = (2 * nt + (quad >> 1)) ^ (l & 7);
                uint2 u = {d0, d1};
                *(uint2*)&Pw[l * 64 + slot8 * 8 + (quad & 1) * 4] = u;
            }
#pragma unroll
            for (int ks = 0; ks < 2; ks++)
                pa[mt][ks] = *(const short8*)&Pw[l * 64 + ((ks * 4 + quad) ^ (l & 7)) * 8];
        }

        // row sums via MFMA (P @ ones)
#pragma unroll
        for (int mt = 0; mt < 2; mt++) {
            lacc[mt] = __builtin_amdgcn_mfma_f32_16x16x32_bf16(pa[mt][0], ones, lacc[mt], 0, 0, 0);
            lacc[mt] = __builtin_amdgcn_mfma_f32_16x16x32_bf16(pa[mt][1], ones, lacc[mt], 0, 0, 0);
        }

        // O += P @ V : V frags shared across mt
#pragma unroll
        for (int nt = 0; nt < 4; nt++) {
            const int rb = (nt * 16 + l) * 64;
            short8 vf0 = *(const short8*)&Vc[rb + ((quad) ^ (l & 7)) * 8];
            short8 vf1 = *(const short8*)&Vc[rb + ((4 + quad) ^ (l & 7)) * 8];
#pragma unroll
            for (int mt = 0; mt < 2; mt++) {
                of[mt][nt] = __builtin_amdgcn_mfma_f32_16x16x32_bf16(pa[mt][0], vf0, of[mt][nt], 0, 0, 0);
                of[mt][nt] = __builtin_amdgcn_mfma_f32_16x16x32_bf16(pa[mt][1], vf1, of[mt][nt], 0, 0, 0);
            }
        }
        cur ^= 1;
    }

    // row-sum partials (lacc C-layout row = quad*4+r; all cols equal)
#pragma unroll
    for (int mt = 0; mt < 2; mt++) {
        if (l == 0) {
#pragma unroll
            for (int r = 0; r < 4; r++)
                lpart[(((size_t)kh * 4 + b) * 12 + h) * 2048 + qt * 256 + w * 32 + mt * 16 + quad * 4 + r] =
                    lacc[mt][r];
        }
    }

    // unnormalized O-partial store
    bf16* op = kh ? opart1 : opart0;
#pragma unroll
    for (int mt = 0; mt < 2; mt++) {
#pragma unroll
        for (int r = 0; r < 4; r++) {
            const int row = qt * 256 + w * 32 + mt * 16 + quad * 4 + r;
#pragma unroll
            for (int nt = 0; nt < 4; nt++)
                op[((size_t)b * 2048 + row) * 768 + h * 64 + nt * 16 + l] =
                    from_f<bf16>(of[mt][nt][r]);
        }
    }
}

// ---------------------------------------------------------------------------
// Combine k-split partials: attn = (O0 + O1) / (l0 + l1). 4 elems/thread.
// ---------------------------------------------------------------------------
__global__ __launch_bounds__(256) void attn_combine(const bf16* __restrict__ o0,
                                                    const bf16* __restrict__ o1,
                                                    const float* __restrict__ lp,
                                                    bf16* __restrict__ outp) {
    const int t = blockIdx.x * 256 + threadIdx.x;   // 0 .. 8192*768/4-1
    const int col4 = t % 192;
    const int row = t / 192;                        // b*2048 + m
    const int b = row >> 11, m = row & 2047;
    const int h = col4 >> 4;
    const float l0 = lp[((size_t)b * 12 + h) * 2048 + m];
    const float l1 = lp[((size_t)(4 + b) * 12 + h) * 2048 + m];
    const float iv = 1.f / (l0 + l1);
    short4v a = ((const short4v*)o0)[t];
    short4v c = ((const short4v*)o1)[t];
    bf16 r[4];
#pragma unroll
    for (int i = 0; i < 4; i++) {
        float f = to_f(__builtin_bit_cast(bf16, a[i])) + to_f(__builtin_bit_cast(bf16, c[i]));
        r[i] = from_f<bf16>(f * iv);
    }
    ((short4v*)outp)[t] = *(short4v*)r;
}

// ---------------------------------------------------------------------------
// Row LayerNorm: out = LN(base + add) * gamma + beta.  D = 768, 256 thr/row.
// ---------------------------------------------------------------------------
template <typename TIN, typename TADD, typename TOUT>
__global__ __launch_bounds__(256) void ln_kernel(const TIN* __restrict__ base,
                                                 const TADD* __restrict__ add,
                                                 const float* __restrict__ gamma,
                                                 const float* __restrict__ beta,
                                                 TOUT* __restrict__ out) {
    const int row = blockIdx.x;
    const int tid = threadIdx.x;
    __shared__ float red[4];
    const size_t o = (size_t)row * 768;
    float v[3];
#pragma unroll
    for (int i = 0; i < 3; i++) {
        int d = tid + i * 256;
        v[i] = to_f(base[o + d]) + to_f(add[o + d]);
    }
    float s = v[0] + v[1] + v[2];
#pragma unroll
    for (int off = 32; off > 0; off >>= 1) s += __shfl_down(s, off, 64);
    const int wave = tid >> 6, lane = tid & 63;
    if (lane == 0) red[wave] = s;
    __syncthreads();
    float mu = (red[0] + red[1] + red[2] + red[3]) * (1.0f / 768.0f);
    float d0 = v[0] - mu, d1 = v[1] - mu, d2 = v[2] - mu;
    float sq = d0 * d0 + d1 * d1 + d2 * d2;
    __syncthreads();
#pragma unroll
    for (int off = 32; off > 0; off >>= 1) sq += __shfl_down(sq, off, 64);
    if (lane == 0) red[wave] = sq;
    __syncthreads();
    float var = (red[0] + red[1] + red[2] + red[3]) * (1.0f / 768.0f);
    float rs = rsqrtf(var + 1e-12f);
#pragma unroll
    for (int i = 0; i < 3; i++) {
        int d = tid + i * 256;
        float y = (v[i] - mu) * rs * gamma[d] + beta[d];
        out[o + d] = from_f<TOUT>(y);
    }
}

// ---------------------------------------------------------------------------
extern "C" void kernel_launch(void* const* d_in, const int* in_sizes, int n_in,
                              void* d_out, int out_size, void* d_ws, size_t ws_size,
                              hipStream_t stream) {
    const float* x    = (const float*)d_in[0];
    const float* mask = (const float*)d_in[1];
    const float* Pq = (const float*)d_in[2];
    const float* Vq = (const float*)d_in[3];
    const float* bq = (const float*)d_in[4];
    const float* Pk = (const float*)d_in[5];
    const float* Vk = (const float*)d_in[6];
    const float* bk = (const float*)d_in[7];
    const float* Pv = (const float*)d_in[8];
    const float* Vv = (const float*)d_in[9];
    const float* bv = (const float*)d_in[10];
    const float* Uo = (const float*)d_in[11];
    const float* Vo = (const float*)d_in[12];
    const float* bo = (const float*)d_in[13];
    const float* U1 = (const float*)d_in[14];
    const float* V1 = (const float*)d_in[15];
    const float* b1 = (const float*)d_in[16];
    const float* U2 = (const float*)d_in[17];
    const float* V2 = (const float*)d_in[18];
    const float* b2 = (const float*)d_in[19];
    const float* g1 = (const float*)d_in[20];
    const float* be1 = (const float*)d_in[21];
    const float* g2 = (const float*)d_in[22];
    const float* be2 = (const float*)d_in[23];

    // ---- workspace layout (bytes) ----
    char* p = (char*)d_ws;
    bf16* Wqkv_t = (bf16*)p;            p += (size_t)2304 * 768 * 2;
    bf16* Wo_t   = (bf16*)p;            p += (size_t)768 * 768 * 2;
    bf16* U1t    = (bf16*)p;            p += (size_t)256 * 768 * 2;
    bf16* V1t    = (bf16*)p;            p += (size_t)3072 * 256 * 2;
    bf16* U2t    = (bf16*)p;            p += (size_t)256 * 3072 * 2;
    bf16* V2t    = (bf16*)p;            p += (size_t)768 * 256 * 2;
    float* bias_qkv = (float*)p;        p += (size_t)2304 * 4;
    float* mask2 = (float*)p;           p += (size_t)8192 * 4;
    bf16* xb     = (bf16*)p;            // aliases x1b (xb dead after LN1)
    bf16* x1b    = xb;                  p += (size_t)8192 * 768 * 2;
    bf16* qkv    = (bf16*)p;            // gbuf aliases qkv+vt (dead after attn)
    bf16* gbuf   = qkv;                 p += (size_t)8192 * 2304 * 2;
    bf16* vtb    = (bf16*)p;            p += (size_t)8192 * 768 * 2;
    bf16* attnb  = (bf16*)p;            // t2 aliases attnb (dead after Wo GEMM)
    bf16* t2     = attnb;               p += (size_t)8192 * 768 * 2;
    char* regR   = p;                   p += (size_t)8192 * 768 * 4;  // 25.2 MB multi-use
    bf16* t1     = (bf16*)p;            p += (size_t)8192 * 256 * 2;
    // region R phases:
    bf16* Vot = (bf16*)regR;                       // prep only
    bf16* Uob = Vot + (size_t)768 * 256;           // prep only
    bf16* opart1 = (bf16*)regR;                    // attention partial (12.6MB)
    float* lpart = (float*)(regR + (size_t)8192 * 768 * 2);  // 786KB
    bf16* y1b = (bf16*)regR;                       // Wo-GEMM out (after combine)
    bf16* y2b = (bf16*)(regR + (size_t)8192 * 768 * 2);  // V2-GEMM out

    // 1) weight prep
    constexpr int N4_X = 8192 * 768 / 4;   // 1,572,864 float4s
    constexpr int N4_UO = 768 * 256 / 4;   // 49,152 float4s
    constexpr int CAST_BLOCKS = (N4_X + N4_UO + 255) / 256;  // 6336
    build_w_qkv_lds<<<dim3(6, 12, 3), 256, 0, stream>>>(Pq, Vq, Pk, Vk, Pv, Vv, Wqkv_t);
    cast_transpose_batch<<<2112, 256, 0, stream>>>(U1, V1, U2, V2, Vo, U1t, V1t, U2t, V2t, Vot);
    cast_f32_bf16_dual<<<CAST_BLOCKS, 256, 0, stream>>>(x, xb, N4_X, Uo, Uob, N4_UO);
    pack_bias_mask<<<35, 256, 0, stream>>>(bq, bk, bv, mask, bias_qkv, mask2);
    gemm_mfma<bf16, 0><<<dim3(6, 6), 256, 0, stream>>>(Vot, Uob, nullptr, Wo_t, 768, 768, 256);

    // 2) fused QKV GEMM
    gemm_mfma<bf16, 0><<<dim3(64, 18), 256, 0, stream>>>(xb, Wqkv_t, bias_qkv, qkv, 8192, 2304, 768);

    // 2.5) transpose V per head
    transpose_v<<<dim3(128, 12), 256, 0, stream>>>(qkv, vtb);

    // 3) flash attention, k-split x2 dbuf, 512-thr blocks + combine
    flash_attn_mfma<<<dim3(8, 12, 8), 512, 0, stream>>>(qkv, vtb, mask2, attnb, opart1, lpart);
    attn_combine<<<6144, 256, 0, stream>>>(attnb, opart1, lpart, attnb);

    // 4) attn @ Wo + bo -> y1b bf16
    gemm_mfma<bf16, 0><<<dim3(64, 6), 256, 0, stream>>>(attnb, Wo_t, bo, y1b, 8192, 768, 768);

    // 5) x1 = LN1(xb + y1b) -> bf16  (xb = bf16 copy of x)
    ln_kernel<bf16, bf16, bf16><<<8192, 256, 0, stream>>>(xb, y1b, g1, be1, x1b);

    // 6) t1 = x1 @ U1  (64-tile: 512 blocks)
    gemm_mfma64<bf16, 0><<<dim3(128, 4), 256, 0, stream>>>(x1b, U1t, nullptr, t1, 8192, 256, 768);

    // 7) g = gelu(t1 @ V1 + b1) -> gbuf bf16
    gemm_mfma<bf16, 1><<<dim3(64, 24), 256, 0, stream>>>(t1, V1t, b1, gbuf, 8192, 3072, 256);

    // 8) t2 = g @ U2  (64-tile: 512 blocks)
    gemm_mfma64<bf16, 0><<<dim3(128, 4), 256, 0, stream>>>(gbuf, U2t, nullptr, t2, 8192, 256, 3072);

    // 9) y = t2 @ V2 + b2 -> y2b bf16
    gemm_mfma<bf16, 0><<<dim3(64, 6), 256, 0, stream>>>(t2, V2t, b2, y2b, 8192, 768, 256);

    // 10) out = LN2(x1 + y2b) -> f32
    ln_kernel<bf16, bf16, float><<<8192, 256, 0, stream>>>(x1b, y2b, g2, be2, (float*)d_out);
}

// Round 13
// 420.205 us; speedup vs baseline: 1.7073x; 1.7073x over previous
//
#include <hip/hip_runtime.h>
#include <hip/hip_bf16.h>
#include <math.h>

typedef __hip_bfloat16 bf16;
typedef __attribute__((ext_vector_type(8))) short short8;   // 8 bf16 = 4 VGPR
typedef __attribute__((ext_vector_type(4))) short short4v;  // 4 bf16
typedef __attribute__((ext_vector_type(4))) float f32x4;

#define C1F 0.18033688011112042f  // 0.125 * log2(e)
#define LOG2E 1.44269504088896f

__device__ __forceinline__ float to_f(float x) { return x; }
__device__ __forceinline__ float to_f(bf16 x) { return __bfloat162float(x); }

template <typename T> __device__ __forceinline__ T from_f(float x);
template <> __device__ __forceinline__ float from_f<float>(float x) { return x; }
template <> __device__ __forceinline__ bf16 from_f<bf16>(float x) { return __float2bfloat16(x); }

__device__ __forceinline__ float gelu_exact(float x) {
    return 0.5f * x * (1.0f + erff(x * 0.70710678118654752f));
}

#define GLD_LDS16(g, l)                                               \
    __builtin_amdgcn_global_load_lds(                                 \
        (const __attribute__((address_space(1))) void*)(g),           \
        (__attribute__((address_space(3))) void*)(l), 16, 0, 0)

// ---------------------------------------------------------------------------
// Fold Q/K/V low-rank weights via LDS staging. Q weights pre-scaled by C1
// (0.125*log2e) so attention's softmax needs no per-score multiply.
// ---------------------------------------------------------------------------
__global__ __launch_bounds__(256) void build_w_qkv_lds(const float* __restrict__ Pq,
                                                       const float* __restrict__ Vq,
                                                       const float* __restrict__ Pk,
                                                       const float* __restrict__ Vk,
                                                       const float* __restrict__ Pv,
                                                       const float* __restrict__ Vv,
                                                       bf16* __restrict__ Wt) {
    const int dt = blockIdx.x;     // 0..5
    const int h = blockIdx.y;      // 0..11
    const int which = blockIdx.z;  // 0..2
    const float* P = (which == 0) ? Pq : (which == 1) ? Pk : Pv;
    const float* V = (which == 0) ? Vq : (which == 1) ? Vk : Vv;
    const float scale = (which == 0) ? C1F : 1.0f;
    __shared__ __align__(16) float Ps[128][36];
    __shared__ __align__(16) float Vs[32][64];
    __shared__ __align__(16) unsigned int Ot[64][68];
    const int tid = threadIdx.x;

    const float* pbase = P + ((size_t)h * 768 + dt * 128) * 32;
#pragma unroll
    for (int i = 0; i < 4; i++) {
        int idx = tid + i * 256;
        float4 v4 = ((const float4*)pbase)[idx];
        *(float4*)&Ps[idx >> 3][(idx & 7) * 4] = v4;
    }
    const float* vbase = V + (size_t)h * 2048;
#pragma unroll
    for (int i = 0; i < 2; i++) {
        int idx = tid + i * 256;
        ((float4*)&Vs[0][0])[idx] = ((const float4*)vbase)[idx];
    }
    __syncthreads();

    const int e = tid & 63, w = tid >> 6;
    float vreg[32];
#pragma unroll
    for (int r = 0; r < 32; r++) vreg[r] = Vs[r][e];

#pragma unroll
    for (int dp = 0; dp < 16; dp++) {
        const int d0 = w * 32 + dp * 2;
        float a0 = 0.f, a1 = 0.f;
#pragma unroll
        for (int r4 = 0; r4 < 8; r4++) {
            float4 p0 = *(const float4*)&Ps[d0][r4 * 4];
            float4 p1 = *(const float4*)&Ps[d0 + 1][r4 * 4];
            a0 += p0.x * vreg[r4 * 4] + p0.y * vreg[r4 * 4 + 1] + p0.z * vreg[r4 * 4 + 2] + p0.w * vreg[r4 * 4 + 3];
            a1 += p1.x * vreg[r4 * 4] + p1.y * vreg[r4 * 4 + 1] + p1.z * vreg[r4 * 4 + 2] + p1.w * vreg[r4 * 4 + 3];
        }
        a0 *= scale;
        a1 *= scale;
        unsigned int lo = (unsigned int)(unsigned short)__builtin_bit_cast(short, from_f<bf16>(a0));
        unsigned int hi = (unsigned int)(unsigned short)__builtin_bit_cast(short, from_f<bf16>(a1));
        Ot[e][w * 16 + dp] = lo | (hi << 16);
    }
    __syncthreads();

    const int erow = tid >> 2, c0 = (tid & 3) * 16;
    bf16* dst = Wt + ((size_t)which * 768 + h * 64 + erow) * 768 + dt * 128 + c0 * 2;
    *(uint4*)(dst) = *(const uint4*)&Ot[erow][c0];
    *(uint4*)(dst + 8) = *(const uint4*)&Ot[erow][c0 + 4];
    *(uint4*)(dst + 16) = *(const uint4*)&Ot[erow][c0 + 8];
    *(uint4*)(dst + 24) = *(const uint4*)&Ot[erow][c0 + 12];
}

// ---------------------------------------------------------------------------
// LDS-tiled cast-transpose: in [R][Cc] f32 -> out [Cc][R] bf16. 32x32 tiles.
// ---------------------------------------------------------------------------
__device__ __forceinline__ void ct_tile(const float* in, bf16* out, int R, int Cc,
                                        int r0, int c0, int tx, int ty) {
    __shared__ float t[32][33];
#pragma unroll
    for (int i = 0; i < 4; i++)
        t[ty + i * 8][tx] = in[(size_t)(r0 + ty + i * 8) * Cc + c0 + tx];
    __syncthreads();
#pragma unroll
    for (int i = 0; i < 4; i++)
        out[(size_t)(c0 + ty + i * 8) * R + r0 + tx] = from_f<bf16>(t[tx][ty + i * 8]);
}

// Batched: U1(768x256), V1(256x3072), U2(3072x256), V2(256x768), Vo(256x768).
__global__ __launch_bounds__(256) void cast_transpose_batch(const float* __restrict__ U1,
                                                            const float* __restrict__ V1,
                                                            const float* __restrict__ U2,
                                                            const float* __restrict__ V2,
                                                            const float* __restrict__ Vo,
                                                            bf16* __restrict__ U1t,
                                                            bf16* __restrict__ V1t,
                                                            bf16* __restrict__ U2t,
                                                            bf16* __restrict__ V2t,
                                                            bf16* __restrict__ Vot) {
    int t = blockIdx.x;
    const float* in;
    bf16* out;
    int R, Cc;
    if (t < 192) { in = U1; out = U1t; R = 768; Cc = 256; }
    else if (t < 960) { t -= 192; in = V1; out = V1t; R = 256; Cc = 3072; }
    else if (t < 1728) { t -= 960; in = U2; out = U2t; R = 3072; Cc = 256; }
    else if (t < 1920) { t -= 1728; in = V2; out = V2t; R = 256; Cc = 768; }
    else { t -= 1920; in = Vo; out = Vot; R = 256; Cc = 768; }
    const int tpr = Cc >> 5;
    ct_tile(in, out, R, Cc, (t / tpr) * 32, (t % tpr) * 32,
            threadIdx.x & 31, threadIdx.x >> 5);
}

// dual cast: x (n4a float4s) then Uo (n4b float4s)
__global__ __launch_bounds__(256) void cast_f32_bf16_dual(const float* __restrict__ a,
                                                          bf16* __restrict__ oa, int n4a,
                                                          const float* __restrict__ bsrc,
                                                          bf16* __restrict__ ob, int n4b) {
    int t = blockIdx.x * 256 + threadIdx.x;
    const float* in;
    bf16* out;
    int i;
    if (t < n4a) { in = a; out = oa; i = t; }
    else if (t < n4a + n4b) { in = bsrc; out = ob; i = t - n4a; }
    else return;
    float4 v = ((const float4*)in)[i];
    bf16 tmp[4] = {from_f<bf16>(v.x), from_f<bf16>(v.y), from_f<bf16>(v.z), from_f<bf16>(v.w)};
    ((short4v*)out)[i] = *(short4v*)tmp;
}

// bias packing (bq pre-scaled by C1) + mask pre-scale (mask2 = mask * log2e)
__global__ __launch_bounds__(256) void pack_bias_mask(const float* __restrict__ bq,
                                                      const float* __restrict__ bk,
                                                      const float* __restrict__ bv,
                                                      const float* __restrict__ mask,
                                                      float* __restrict__ bias_out,
                                                      float* __restrict__ mask2) {
    int t = blockIdx.x * 256 + threadIdx.x;
    if (t < 768) {
        bias_out[t] = bq[t] * C1F;
        bias_out[768 + t] = bk[t];
        bias_out[1536 + t] = bv[t];
    }
    int m = t - 768;
    if (m >= 0 && m < 8192) mask2[m] = mask[m] * LOG2E;
}

// ---------------------------------------------------------------------------
// MFMA GEMM: C[M,N] = A[M,K](bf16,row-major) @ Bt[N,K](bf16,K-major) (+bias)(+GELU)
// 128x128 tile, BK=32, 256 thr = 4 waves (2x2 of 64x64). m97 structure.
// ---------------------------------------------------------------------------
template <typename TOUT, int EPI>
__global__ __launch_bounds__(256) void gemm_mfma(const bf16* __restrict__ A,
                                                 const bf16* __restrict__ Bt,
                                                 const float* __restrict__ bias,
                                                 TOUT* __restrict__ C,
                                                 int M, int N, int K) {
    __shared__ __align__(16) bf16 As[128 * 32];
    __shared__ __align__(16) bf16 Bs[128 * 32];
    const int tid = threadIdx.x;
    const int w = tid >> 6, lane = tid & 63;
    const int l = lane & 15, quad = lane >> 4;
    const int wm = w >> 1, wn = w & 1;
    const int m0 = blockIdx.x * 128, n0 = blockIdx.y * 128;

    const int r_in = lane >> 2;
    const int slot = lane & 3;
    const int rA0 = 2 * w * 16 + r_in, rA1 = rA0 + 16;
    const int q0 = slot ^ ((rA0 >> 1) & 3);
    const int q1 = slot ^ ((rA1 >> 1) & 3);
    const bf16* a0 = A + (size_t)(m0 + rA0) * K + q0 * 8;
    const bf16* a1 = A + (size_t)(m0 + rA1) * K + q1 * 8;
    const bf16* b0 = Bt + (size_t)(n0 + rA0) * K + q0 * 8;
    const bf16* b1 = Bt + (size_t)(n0 + rA1) * K + q1 * 8;
    bf16* lA0 = As + 2 * w * 512;
    bf16* lA1 = lA0 + 512;
    bf16* lB0 = Bs + 2 * w * 512;
    bf16* lB1 = lB0 + 512;

    const int swz = (quad ^ ((l >> 1) & 3)) * 8;
    f32x4 acc[4][4] = {};

    for (int k0 = 0; k0 < K; k0 += 32) {
        GLD_LDS16(a0 + k0, lA0);
        GLD_LDS16(a1 + k0, lA1);
        GLD_LDS16(b0 + k0, lB0);
        GLD_LDS16(b1 + k0, lB1);
        __syncthreads();
        short8 af[4], bfr[4];
#pragma unroll
        for (int mt = 0; mt < 4; mt++)
            af[mt] = *(const short8*)&As[(wm * 64 + mt * 16 + l) * 32 + swz];
#pragma unroll
        for (int nt = 0; nt < 4; nt++)
            bfr[nt] = *(const short8*)&Bs[(wn * 64 + nt * 16 + l) * 32 + swz];
#pragma unroll
        for (int mt = 0; mt < 4; mt++)
#pragma unroll
            for (int nt = 0; nt < 4; nt++)
                acc[mt][nt] = __builtin_amdgcn_mfma_f32_16x16x32_bf16(af[mt], bfr[nt], acc[mt][nt], 0, 0, 0);
        __syncthreads();
    }

    float bs[4];
#pragma unroll
    for (int nt = 0; nt < 4; nt++)
        bs[nt] = bias ? bias[n0 + wn * 64 + nt * 16 + l] : 0.f;
#pragma unroll
    for (int mt = 0; mt < 4; mt++) {
#pragma unroll
        for (int nt = 0; nt < 4; nt++) {
            const int col = n0 + wn * 64 + nt * 16 + l;
#pragma unroll
            for (int r = 0; r < 4; r++) {
                const int row = m0 + wm * 64 + mt * 16 + quad * 4 + r;
                float val = acc[mt][nt][r] + bs[nt];
                if (EPI == 1) val = gelu_exact(val);
                C[(size_t)row * N + col] = from_f<TOUT>(val);
            }
        }
    }
}

// ---------------------------------------------------------------------------
// 64x64-tile MFMA GEMM for narrow-N problems (N=256).
// ---------------------------------------------------------------------------
template <typename TOUT, int EPI>
__global__ __launch_bounds__(256) void gemm_mfma64(const bf16* __restrict__ A,
                                                   const bf16* __restrict__ Bt,
                                                   const float* __restrict__ bias,
                                                   TOUT* __restrict__ C,
                                                   int M, int N, int K) {
    __shared__ __align__(16) bf16 As[64 * 32];
    __shared__ __align__(16) bf16 Bs[64 * 32];
    const int tid = threadIdx.x;
    const int w = tid >> 6, lane = tid & 63;
    const int l = lane & 15, quad = lane >> 4;
    const int wm = w >> 1, wn = w & 1;
    const int m0 = blockIdx.x * 64, n0 = blockIdx.y * 64;

    const int cid = tid;
    const int srow = cid >> 2, slot = cid & 3;
    const int gq = slot ^ ((srow >> 1) & 3);
    const bf16* ag = A + (size_t)(m0 + srow) * K + gq * 8;
    const bf16* bg = Bt + (size_t)(n0 + srow) * K + gq * 8;
    bf16* lA = As + w * 512;
    bf16* lB = Bs + w * 512;

    f32x4 acc[2][2] = {};

    for (int k0 = 0; k0 < K; k0 += 32) {
        GLD_LDS16(ag + k0, lA);
        GLD_LDS16(bg + k0, lB);
        __syncthreads();
        short8 af[2], bfr[2];
#pragma unroll
        for (int mt = 0; mt < 2; mt++) {
            const int row = wm * 32 + mt * 16 + l;
            af[mt] = *(const short8*)&As[row * 32 + (quad ^ ((row >> 1) & 3)) * 8];
        }
#pragma unroll
        for (int nt = 0; nt < 2; nt++) {
            const int row = wn * 32 + nt * 16 + l;
            bfr[nt] = *(const short8*)&Bs[row * 32 + (quad ^ ((row >> 1) & 3)) * 8];
        }
#pragma unroll
        for (int mt = 0; mt < 2; mt++)
#pragma unroll
            for (int nt = 0; nt < 2; nt++)
                acc[mt][nt] = __builtin_amdgcn_mfma_f32_16x16x32_bf16(af[mt], bfr[nt], acc[mt][nt], 0, 0, 0);
        __syncthreads();
    }

#pragma unroll
    for (int mt = 0; mt < 2; mt++) {
#pragma unroll
        for (int nt = 0; nt < 2; nt++) {
            const int col = n0 + wn * 32 + nt * 16 + l;
            const float bsv = bias ? bias[col] : 0.f;
#pragma unroll
            for (int r = 0; r < 4; r++) {
                const int row = m0 + wm * 32 + mt * 16 + quad * 4 + r;
                float val = acc[mt][nt][r] + bsv;
                if (EPI == 1) val = gelu_exact(val);
                C[(size_t)row * N + col] = from_f<TOUT>(val);
            }
        }
    }
}

// ---------------------------------------------------------------------------
// Transpose V per head: qkv [b][m][2304] (V at col 1536+h*64+e) -> vt [b][h][e][m]
// ---------------------------------------------------------------------------
__global__ __launch_bounds__(256) void transpose_v(const bf16* __restrict__ qkv,
                                                   bf16* __restrict__ vt) {
    __shared__ __align__(16) bf16 t[64][72];
    const int m0 = blockIdx.x * 64;
    const int h = blockIdx.y;
    const int tid = threadIdx.x;
    const int r = tid >> 2, c0 = (tid & 3) * 16;
    {
        const size_t g = (size_t)(m0 + r) * 2304 + 1536 + h * 64 + c0;
        *(short8*)&t[r][c0] = *(const short8*)(qkv + g);
        *(short8*)&t[r][c0 + 8] = *(const short8*)(qkv + g + 8);
    }
    __syncthreads();
    const int b = m0 >> 11, mm = m0 & 2047;
    const int e = tid >> 2, mi0 = (tid & 3) * 16;
    bf16 tmp[16];
#pragma unroll
    for (int j = 0; j < 16; j++) tmp[j] = t[mi0 + j][e];
    bf16* dst = vt + (((size_t)b * 12 + h) * 64 + e) * 2048 + mm + mi0;
    *(short8*)dst = *(short8*)&tmp[0];
    *(short8*)(dst + 8) = *(short8*)&tmp[8];
}

// ---------------------------------------------------------------------------
// MFMA flash attention (R10-proven config): 16x16x32 S^T, k-split x2,
// double-buffered staging, 256 thr = 4 waves, 128 q-rows/block.
// NOTE: R12's 512-thr/(512,6) variant forced a ~85-reg unified VGPR+AGPR cap
// -> 40 VGPRs + spill loop -> 1.7 GB scratch traffic. This kernel needs ~104
// regs; (256,4) caps at 128 which fits. Do not raise the waves/EU target.
// LDS: 2x8K (K) + 2x8K (V) + 8K (P) = 40KB -> 4 blocks/CU.
// ---------------------------------------------------------------------------
__global__ __launch_bounds__(256, 4) void flash_attn_mfma(const bf16* __restrict__ qkv,
                                                          const bf16* __restrict__ vt,
                                                          const float* __restrict__ mask2,
                                                          bf16* __restrict__ opart0,
                                                          bf16* __restrict__ opart1,
                                                          float* __restrict__ lpart) {
    const int qt = blockIdx.x, h = blockIdx.y;
    const int b = blockIdx.z >> 1, kh = blockIdx.z & 1;
    const int tid = threadIdx.x;
    const int w = tid >> 6, lane = tid & 63;
    const int l = lane & 15, quad = lane >> 4;

    __shared__ __align__(16) bf16 Ks[2][64 * 64];
    __shared__ __align__(16) bf16 Vs[2][64 * 64];
    __shared__ __align__(16) bf16 Ps[4 * 16 * 64];   // 16 rows/wave

    // Q fragments (B-layout: [k=d][n=q]) for 2 m-tiles (Q pre-scaled by C1)
    short8 qf[2][2];
#pragma unroll
    for (int mt = 0; mt < 2; mt++) {
        const int qrow = qt * 128 + w * 32 + mt * 16 + l;
        const bf16* qp = qkv + ((size_t)b * 2048 + qrow) * 2304 + h * 64 + quad * 8;
        qf[mt][0] = *(const short8*)qp;
        qf[mt][1] = *(const short8*)(qp + 32);
    }

    short8 ones;
#pragma unroll
    for (int i = 0; i < 8; i++) ones[i] = (short)0x3F80;  // bf16 1.0

    f32x4 of[2][4] = {};
    f32x4 lacc[2] = {};
    bf16* Pw = Ps + w * 1024;

    // loop-carried staging pointers (strength-reduced)
    const int kc0 = kh * 1024;
    int ldst[2];
    const bf16* kg[2];
    const bf16* vg[2];
#pragma unroll
    for (int i = 0; i < 2; i++) {
        const int cid = (w * 2 + i) * 64 + lane;
        const int row = cid >> 3, slot = cid & 7;
        const int gq = slot ^ (row & 7);
        ldst[i] = cid * 8;
        kg[i] = qkv + ((size_t)b * 2048 + kc0 + row) * 2304 + 768 + h * 64 + gq * 8;
        vg[i] = vt + (((size_t)b * 12 + h) * 64 + row) * 2048 + kc0 + gq * 8;
    }
    const float* mp = mask2 + (size_t)b * 2048 + kc0 + quad * 4;

    auto stage = [&](int buf) {
#pragma unroll
        for (int i = 0; i < 2; i++) {
            GLD_LDS16(kg[i], &Ks[buf][ldst[i]]);
            GLD_LDS16(vg[i], &Vs[buf][ldst[i]]);
            kg[i] += 64 * 2304;
            vg[i] += 64;
        }
    };

    int cur = 0;
    stage(0);

#pragma unroll 2
    for (int it = 0; it < 16; it++) {
        __syncthreads();  // buf[cur] staged; all waves done reading buf[cur^1]
        float4 mrow[4];
#pragma unroll
        for (int nt = 0; nt < 4; nt++) mrow[nt] = *(const float4*)(mp + nt * 16);
        mp += 64;
        if (it < 15) stage(cur ^ 1);  // prefetch next tile

        const bf16* Kc = Ks[cur];
        const bf16* Vc = Vs[cur];

        // S^T = K · Q^T + mask (acc seeded with log2e-scaled mask rows)
        f32x4 st[2][4];
#pragma unroll
        for (int nt = 0; nt < 4; nt++) {
            const int rb = (nt * 16 + l) * 64;
            short8 kf0 = *(const short8*)&Kc[rb + ((quad) ^ (l & 7)) * 8];
            short8 kf1 = *(const short8*)&Kc[rb + ((4 + quad) ^ (l & 7)) * 8];
#pragma unroll
            for (int mt = 0; mt < 2; mt++) {
                f32x4 a = {mrow[nt].x, mrow[nt].y, mrow[nt].z, mrow[nt].w};
                a = __builtin_amdgcn_mfma_f32_16x16x32_bf16(kf0, qf[mt][0], a, 0, 0, 0);
                a = __builtin_amdgcn_mfma_f32_16x16x32_bf16(kf1, qf[mt][1], a, 0, 0, 0);
                st[mt][nt] = a;
            }
        }

        // P = exp2(st); pack pairs with v_perm (truncation); per-mt sequential
        // store + A-frag read (Ps is 16 rows; same-wave LDS ordering is safe)
        short8 pa[2][2];
#pragma unroll
        for (int mt = 0; mt < 2; mt++) {
#pragma unroll
            for (int nt = 0; nt < 4; nt++) {
                float p0 = exp2f(st[mt][nt][0]);
                float p1 = exp2f(st[mt][nt][1]);
                float p2 = exp2f(st[mt][nt][2]);
                float p3 = exp2f(st[mt][nt][3]);
                unsigned d0 = __builtin_amdgcn_perm(__builtin_bit_cast(unsigned, p1),
                                                    __builtin_bit_cast(unsigned, p0), 0x07060302u);
                unsigned d1 = __builtin_amdgcn_perm(__builtin_bit_cast(unsigned, p3),
                                                    __builtin_bit_cast(unsigned, p2), 0x07060302u);
                const int slot8 = (2 * nt + (quad >> 1)) ^ (l & 7);
                uint2 u = {d0, d1};
                *(uint2*)&Pw[l * 64 + slot8 * 8 + (quad & 1) * 4] = u;
            }
#pragma unroll
            for (int ks = 0; ks < 2; ks++)
                pa[mt][ks] = *(const short8*)&Pw[l * 64 + ((ks * 4 + quad) ^ (l & 7)) * 8];
        }

        // row sums via MFMA (P @ ones)
#pragma unroll
        for (int mt = 0; mt < 2; mt++) {
            lacc[mt] = __builtin_amdgcn_mfma_f32_16x16x32_bf16(pa[mt][0], ones, lacc[mt], 0, 0, 0);
            lacc[mt] = __builtin_amdgcn_mfma_f32_16x16x32_bf16(pa[mt][1], ones, lacc[mt], 0, 0, 0);
        }

        // O += P @ V : V frags shared across mt
#pragma unroll
        for (int nt = 0; nt < 4; nt++) {
            const int rb = (nt * 16 + l) * 64;
            short8 vf0 = *(const short8*)&Vc[rb + ((quad) ^ (l & 7)) * 8];
            short8 vf1 = *(const short8*)&Vc[rb + ((4 + quad) ^ (l & 7)) * 8];
#pragma unroll
            for (int mt = 0; mt < 2; mt++) {
                of[mt][nt] = __builtin_amdgcn_mfma_f32_16x16x32_bf16(pa[mt][0], vf0, of[mt][nt], 0, 0, 0);
                of[mt][nt] = __builtin_amdgcn_mfma_f32_16x16x32_bf16(pa[mt][1], vf1, of[mt][nt], 0, 0, 0);
            }
        }
        cur ^= 1;
    }

    // row-sum partials (lacc C-layout row = quad*4+r; all cols equal)
#pragma unroll
    for (int mt = 0; mt < 2; mt++) {
        if (l == 0) {
#pragma unroll
            for (int r = 0; r < 4; r++)
                lpart[(((size_t)kh * 4 + b) * 12 + h) * 2048 + qt * 128 + w * 32 + mt * 16 + quad * 4 + r] =
                    lacc[mt][r];
        }
    }

    // unnormalized O-partial store
    bf16* op = kh ? opart1 : opart0;
#pragma unroll
    for (int mt = 0; mt < 2; mt++) {
#pragma unroll
        for (int r = 0; r < 4; r++) {
            const int row = qt * 128 + w * 32 + mt * 16 + quad * 4 + r;
#pragma unroll
            for (int nt = 0; nt < 4; nt++)
                op[((size_t)b * 2048 + row) * 768 + h * 64 + nt * 16 + l] =
                    from_f<bf16>(of[mt][nt][r]);
        }
    }
}

// ---------------------------------------------------------------------------
// Combine k-split partials: attn = (O0 + O1) / (l0 + l1). 4 elems/thread.
// ---------------------------------------------------------------------------
__global__ __launch_bounds__(256) void attn_combine(const bf16* __restrict__ o0,
                                                    const bf16* __restrict__ o1,
                                                    const float* __restrict__ lp,
                                                    bf16* __restrict__ outp) {
    const int t = blockIdx.x * 256 + threadIdx.x;   // 0 .. 8192*768/4-1
    const int col4 = t % 192;
    const int row = t / 192;                        // b*2048 + m
    const int b = row >> 11, m = row & 2047;
    const int h = col4 >> 4;
    const float l0 = lp[((size_t)b * 12 + h) * 2048 + m];
    const float l1 = lp[((size_t)(4 + b) * 12 + h) * 2048 + m];
    const float iv = 1.f / (l0 + l1);
    short4v a = ((const short4v*)o0)[t];
    short4v c = ((const short4v*)o1)[t];
    bf16 r[4];
#pragma unroll
    for (int i = 0; i < 4; i++) {
        float f = to_f(__builtin_bit_cast(bf16, a[i])) + to_f(__builtin_bit_cast(bf16, c[i]));
        r[i] = from_f<bf16>(f * iv);
    }
    ((short4v*)outp)[t] = *(short4v*)r;
}

// ---------------------------------------------------------------------------
// Row LayerNorm: out = LN(base + add) * gamma + beta.  D = 768, 256 thr/row.
// ---------------------------------------------------------------------------
template <typename TIN, typename TADD, typename TOUT>
__global__ __launch_bounds__(256) void ln_kernel(const TIN* __restrict__ base,
                                                 const TADD* __restrict__ add,
                                                 const float* __restrict__ gamma,
                                                 const float* __restrict__ beta,
                                                 TOUT* __restrict__ out) {
    const int row = blockIdx.x;
    const int tid = threadIdx.x;
    __shared__ float red[4];
    const size_t o = (size_t)row * 768;
    float v[3];
#pragma unroll
    for (int i = 0; i < 3; i++) {
        int d = tid + i * 256;
        v[i] = to_f(base[o + d]) + to_f(add[o + d]);
    }
    float s = v[0] + v[1] + v[2];
#pragma unroll
    for (int off = 32; off > 0; off >>= 1) s += __shfl_down(s, off, 64);
    const int wave = tid >> 6, lane = tid & 63;
    if (lane == 0) red[wave] = s;
    __syncthreads();
    float mu = (red[0] + red[1] + red[2] + red[3]) * (1.0f / 768.0f);
    float d0 = v[0] - mu, d1 = v[1] - mu, d2 = v[2] - mu;
    float sq = d0 * d0 + d1 * d1 + d2 * d2;
    __syncthreads();
#pragma unroll
    for (int off = 32; off > 0; off >>= 1) sq += __shfl_down(sq, off, 64);
    if (lane == 0) red[wave] = sq;
    __syncthreads();
    float var = (red[0] + red[1] + red[2] + red[3]) * (1.0f / 768.0f);
    float rs = rsqrtf(var + 1e-12f);
#pragma unroll
    for (int i = 0; i < 3; i++) {
        int d = tid + i * 256;
        float y = (v[i] - mu) * rs * gamma[d] + beta[d];
        out[o + d] = from_f<TOUT>(y);
    }
}

// ---------------------------------------------------------------------------
extern "C" void kernel_launch(void* const* d_in, const int* in_sizes, int n_in,
                              void* d_out, int out_size, void* d_ws, size_t ws_size,
                              hipStream_t stream) {
    const float* x    = (const float*)d_in[0];
    const float* mask = (const float*)d_in[1];
    const float* Pq = (const float*)d_in[2];
    const float* Vq = (const float*)d_in[3];
    const float* bq = (const float*)d_in[4];
    const float* Pk = (const float*)d_in[5];
    const float* Vk = (const float*)d_in[6];
    const float* bk = (const float*)d_in[7];
    const float* Pv = (const float*)d_in[8];
    const float* Vv = (const float*)d_in[9];
    const float* bv = (const float*)d_in[10];
    const float* Uo = (const float*)d_in[11];
    const float* Vo = (const float*)d_in[12];
    const float* bo = (const float*)d_in[13];
    const float* U1 = (const float*)d_in[14];
    const float* V1 = (const float*)d_in[15];
    const float* b1 = (const float*)d_in[16];
    const float* U2 = (const float*)d_in[17];
    const float* V2 = (const float*)d_in[18];
    const float* b2 = (const float*)d_in[19];
    const float* g1 = (const float*)d_in[20];
    const float* be1 = (const float*)d_in[21];
    const float* g2 = (const float*)d_in[22];
    const float* be2 = (const float*)d_in[23];

    // ---- workspace layout (bytes) ----
    char* p = (char*)d_ws;
    bf16* Wqkv_t = (bf16*)p;            p += (size_t)2304 * 768 * 2;
    bf16* Wo_t   = (bf16*)p;            p += (size_t)768 * 768 * 2;
    bf16* U1t    = (bf16*)p;            p += (size_t)256 * 768 * 2;
    bf16* V1t    = (bf16*)p;            p += (size_t)3072 * 256 * 2;
    bf16* U2t    = (bf16*)p;            p += (size_t)256 * 3072 * 2;
    bf16* V2t    = (bf16*)p;            p += (size_t)768 * 256 * 2;
    float* bias_qkv = (float*)p;        p += (size_t)2304 * 4;
    float* mask2 = (float*)p;           p += (size_t)8192 * 4;
    bf16* xb     = (bf16*)p;            // aliases x1b (xb dead after LN1)
    bf16* x1b    = xb;                  p += (size_t)8192 * 768 * 2;
    bf16* qkv    = (bf16*)p;            // gbuf aliases qkv+vt (dead after attn)
    bf16* gbuf   = qkv;                 p += (size_t)8192 * 2304 * 2;
    bf16* vtb    = (bf16*)p;            p += (size_t)8192 * 768 * 2;
    bf16* attnb  = (bf16*)p;            // t2 aliases attnb (dead after Wo GEMM)
    bf16* t2     = attnb;               p += (size_t)8192 * 768 * 2;
    char* regR   = p;                   p += (size_t)8192 * 768 * 4;  // 25.2 MB multi-use
    bf16* t1     = (bf16*)p;            p += (size_t)8192 * 256 * 2;
    // region R phases:
    bf16* Vot = (bf16*)regR;                       // prep only
    bf16* Uob = Vot + (size_t)768 * 256;           // prep only
    bf16* opart1 = (bf16*)regR;                    // attention partial (12.6MB)
    float* lpart = (float*)(regR + (size_t)8192 * 768 * 2);  // 786KB
    bf16* y1b = (bf16*)regR;                       // Wo-GEMM out (after combine)
    bf16* y2b = (bf16*)(regR + (size_t)8192 * 768 * 2);  // V2-GEMM out

    // 1) weight prep
    constexpr int N4_X = 8192 * 768 / 4;   // 1,572,864 float4s
    constexpr int N4_UO = 768 * 256 / 4;   // 49,152 float4s
    constexpr int CAST_BLOCKS = (N4_X + N4_UO + 255) / 256;  // 6336
    build_w_qkv_lds<<<dim3(6, 12, 3), 256, 0, stream>>>(Pq, Vq, Pk, Vk, Pv, Vv, Wqkv_t);
    cast_transpose_batch<<<2112, 256, 0, stream>>>(U1, V1, U2, V2, Vo, U1t, V1t, U2t, V2t, Vot);
    cast_f32_bf16_dual<<<CAST_BLOCKS, 256, 0, stream>>>(x, xb, N4_X, Uo, Uob, N4_UO);
    pack_bias_mask<<<35, 256, 0, stream>>>(bq, bk, bv, mask, bias_qkv, mask2);
    gemm_mfma<bf16, 0><<<dim3(6, 6), 256, 0, stream>>>(Vot, Uob, nullptr, Wo_t, 768, 768, 256);

    // 2) fused QKV GEMM
    gemm_mfma<bf16, 0><<<dim3(64, 18), 256, 0, stream>>>(xb, Wqkv_t, bias_qkv, qkv, 8192, 2304, 768);

    // 2.5) transpose V per head
    transpose_v<<<dim3(128, 12), 256, 0, stream>>>(qkv, vtb);

    // 3) flash attention, k-split x2 dbuf (R10 config) + combine
    flash_attn_mfma<<<dim3(16, 12, 8), 256, 0, stream>>>(qkv, vtb, mask2, attnb, opart1, lpart);
    attn_combine<<<6144, 256, 0, stream>>>(attnb, opart1, lpart, attnb);

    // 4) attn @ Wo + bo -> y1b bf16
    gemm_mfma<bf16, 0><<<dim3(64, 6), 256, 0, stream>>>(attnb, Wo_t, bo, y1b, 8192, 768, 768);

    // 5) x1 = LN1(xb + y1b) -> bf16  (xb = bf16 copy of x)
    ln_kernel<bf16, bf16, bf16><<<8192, 256, 0, stream>>>(xb, y1b, g1, be1, x1b);

    // 6) t1 = x1 @ U1  (64-tile: 512 blocks)
    gemm_mfma64<bf16, 0><<<dim3(128, 4), 256, 0, stream>>>(x1b, U1t, nullptr, t1, 8192, 256, 768);

    // 7) g = gelu(t1 @ V1 + b1) -> gbuf bf16
    gemm_mfma<bf16, 1><<<dim3(64, 24), 256, 0, stream>>>(t1, V1t, b1, gbuf, 8192, 3072, 256);

    // 8) t2 = g @ U2  (64-tile: 512 blocks)
    gemm_mfma64<bf16, 0><<<dim3(128, 4), 256, 0, stream>>>(gbuf, U2t, nullptr, t2, 8192, 256, 3072);

    // 9) y = t2 @ V2 + b2 -> y2b bf16
    gemm_mfma<bf16, 0><<<dim3(64, 6), 256, 0, stream>>>(t2, V2t, b2, y2b, 8192, 768, 256);

    // 10) out = LN2(x1 + y2b) -> f32
    ln_kernel<bf16, bf16, float><<<8192, 256, 0, stream>>>(x1b, y2b, g2, be2, (float*)d_out);
}

// Round 14
// 417.302 us; speedup vs baseline: 1.7192x; 1.0070x over previous
//
#include <hip/hip_runtime.h>
#include <hip/hip_bf16.h>
#include <math.h>

typedef __hip_bfloat16 bf16;
typedef __attribute__((ext_vector_type(8))) short short8;   // 8 bf16 = 4 VGPR
typedef __attribute__((ext_vector_type(4))) short short4v;  // 4 bf16
typedef __attribute__((ext_vector_type(4))) float f32x4;

#define C1F 0.18033688011112042f  // 0.125 * log2(e)
#define LOG2E 1.44269504088896f

__device__ __forceinline__ float to_f(float x) { return x; }
__device__ __forceinline__ float to_f(bf16 x) { return __bfloat162float(x); }

template <typename T> __device__ __forceinline__ T from_f(float x);
template <> __device__ __forceinline__ float from_f<float>(float x) { return x; }
template <> __device__ __forceinline__ bf16 from_f<bf16>(float x) { return __float2bfloat16(x); }

__device__ __forceinline__ float gelu_exact(float x) {
    return 0.5f * x * (1.0f + erff(x * 0.70710678118654752f));
}

#define GLD_LDS16(g, l)                                               \
    __builtin_amdgcn_global_load_lds(                                 \
        (const __attribute__((address_space(1))) void*)(g),           \
        (__attribute__((address_space(3))) void*)(l), 16, 0, 0)

// ---------------------------------------------------------------------------
// Fold Q/K/V low-rank weights via LDS staging. Q weights pre-scaled by C1.
// ---------------------------------------------------------------------------
__global__ __launch_bounds__(256) void build_w_qkv_lds(const float* __restrict__ Pq,
                                                       const float* __restrict__ Vq,
                                                       const float* __restrict__ Pk,
                                                       const float* __restrict__ Vk,
                                                       const float* __restrict__ Pv,
                                                       const float* __restrict__ Vv,
                                                       bf16* __restrict__ Wt) {
    const int dt = blockIdx.x;     // 0..5
    const int h = blockIdx.y;      // 0..11
    const int which = blockIdx.z;  // 0..2
    const float* P = (which == 0) ? Pq : (which == 1) ? Pk : Pv;
    const float* V = (which == 0) ? Vq : (which == 1) ? Vk : Vv;
    const float scale = (which == 0) ? C1F : 1.0f;
    __shared__ __align__(16) float Ps[128][36];
    __shared__ __align__(16) float Vs[32][64];
    __shared__ __align__(16) unsigned int Ot[64][68];
    const int tid = threadIdx.x;

    const float* pbase = P + ((size_t)h * 768 + dt * 128) * 32;
#pragma unroll
    for (int i = 0; i < 4; i++) {
        int idx = tid + i * 256;
        float4 v4 = ((const float4*)pbase)[idx];
        *(float4*)&Ps[idx >> 3][(idx & 7) * 4] = v4;
    }
    const float* vbase = V + (size_t)h * 2048;
#pragma unroll
    for (int i = 0; i < 2; i++) {
        int idx = tid + i * 256;
        ((float4*)&Vs[0][0])[idx] = ((const float4*)vbase)[idx];
    }
    __syncthreads();

    const int e = tid & 63, w = tid >> 6;
    float vreg[32];
#pragma unroll
    for (int r = 0; r < 32; r++) vreg[r] = Vs[r][e];

#pragma unroll
    for (int dp = 0; dp < 16; dp++) {
        const int d0 = w * 32 + dp * 2;
        float a0 = 0.f, a1 = 0.f;
#pragma unroll
        for (int r4 = 0; r4 < 8; r4++) {
            float4 p0 = *(const float4*)&Ps[d0][r4 * 4];
            float4 p1 = *(const float4*)&Ps[d0 + 1][r4 * 4];
            a0 += p0.x * vreg[r4 * 4] + p0.y * vreg[r4 * 4 + 1] + p0.z * vreg[r4 * 4 + 2] + p0.w * vreg[r4 * 4 + 3];
            a1 += p1.x * vreg[r4 * 4] + p1.y * vreg[r4 * 4 + 1] + p1.z * vreg[r4 * 4 + 2] + p1.w * vreg[r4 * 4 + 3];
        }
        a0 *= scale;
        a1 *= scale;
        unsigned int lo = (unsigned int)(unsigned short)__builtin_bit_cast(short, from_f<bf16>(a0));
        unsigned int hi = (unsigned int)(unsigned short)__builtin_bit_cast(short, from_f<bf16>(a1));
        Ot[e][w * 16 + dp] = lo | (hi << 16);
    }
    __syncthreads();

    const int erow = tid >> 2, c0 = (tid & 3) * 16;
    bf16* dst = Wt + ((size_t)which * 768 + h * 64 + erow) * 768 + dt * 128 + c0 * 2;
    *(uint4*)(dst) = *(const uint4*)&Ot[erow][c0];
    *(uint4*)(dst + 8) = *(const uint4*)&Ot[erow][c0 + 4];
    *(uint4*)(dst + 16) = *(const uint4*)&Ot[erow][c0 + 8];
    *(uint4*)(dst + 24) = *(const uint4*)&Ot[erow][c0 + 12];
}

// ---------------------------------------------------------------------------
// LDS-tiled cast-transpose: in [R][Cc] f32 -> out [Cc][R] bf16. 32x32 tiles.
// ---------------------------------------------------------------------------
__device__ __forceinline__ void ct_tile(const float* in, bf16* out, int R, int Cc,
                                        int r0, int c0, int tx, int ty) {
    __shared__ float t[32][33];
#pragma unroll
    for (int i = 0; i < 4; i++)
        t[ty + i * 8][tx] = in[(size_t)(r0 + ty + i * 8) * Cc + c0 + tx];
    __syncthreads();
#pragma unroll
    for (int i = 0; i < 4; i++)
        out[(size_t)(c0 + ty + i * 8) * R + r0 + tx] = from_f<bf16>(t[tx][ty + i * 8]);
}

// Batched: U1(768x256), V1(256x3072), U2(3072x256), V2(256x768), Vo(256x768).
__global__ __launch_bounds__(256) void cast_transpose_batch(const float* __restrict__ U1,
                                                            const float* __restrict__ V1,
                                                            const float* __restrict__ U2,
                                                            const float* __restrict__ V2,
                                                            const float* __restrict__ Vo,
                                                            bf16* __restrict__ U1t,
                                                            bf16* __restrict__ V1t,
                                                            bf16* __restrict__ U2t,
                                                            bf16* __restrict__ V2t,
                                                            bf16* __restrict__ Vot) {
    int t = blockIdx.x;
    const float* in;
    bf16* out;
    int R, Cc;
    if (t < 192) { in = U1; out = U1t; R = 768; Cc = 256; }
    else if (t < 960) { t -= 192; in = V1; out = V1t; R = 256; Cc = 3072; }
    else if (t < 1728) { t -= 960; in = U2; out = U2t; R = 3072; Cc = 256; }
    else if (t < 1920) { t -= 1728; in = V2; out = V2t; R = 256; Cc = 768; }
    else { t -= 1920; in = Vo; out = Vot; R = 256; Cc = 768; }
    const int tpr = Cc >> 5;
    ct_tile(in, out, R, Cc, (t / tpr) * 32, (t % tpr) * 32,
            threadIdx.x & 31, threadIdx.x >> 5);
}

// dual cast: x (n4a float4s) then Uo (n4b float4s)
__global__ __launch_bounds__(256) void cast_f32_bf16_dual(const float* __restrict__ a,
                                                          bf16* __restrict__ oa, int n4a,
                                                          const float* __restrict__ bsrc,
                                                          bf16* __restrict__ ob, int n4b) {
    int t = blockIdx.x * 256 + threadIdx.x;
    const float* in;
    bf16* out;
    int i;
    if (t < n4a) { in = a; out = oa; i = t; }
    else if (t < n4a + n4b) { in = bsrc; out = ob; i = t - n4a; }
    else return;
    float4 v = ((const float4*)in)[i];
    bf16 tmp[4] = {from_f<bf16>(v.x), from_f<bf16>(v.y), from_f<bf16>(v.z), from_f<bf16>(v.w)};
    ((short4v*)out)[i] = *(short4v*)tmp;
}

// bias packing (bq pre-scaled by C1) + mask pre-scale (mask2 = mask * log2e)
__global__ __launch_bounds__(256) void pack_bias_mask(const float* __restrict__ bq,
                                                      const float* __restrict__ bk,
                                                      const float* __restrict__ bv,
                                                      const float* __restrict__ mask,
                                                      float* __restrict__ bias_out,
                                                      float* __restrict__ mask2) {
    int t = blockIdx.x * 256 + threadIdx.x;
    if (t < 768) {
        bias_out[t] = bq[t] * C1F;
        bias_out[768 + t] = bk[t];
        bias_out[1536 + t] = bv[t];
    }
    int m = t - 768;
    if (m >= 0 && m < 8192) mask2[m] = mask[m] * LOG2E;
}

// ---------------------------------------------------------------------------
// MFMA GEMM, DOUBLE-BUFFERED: C = A(row-major) @ Bt(K-major) (+bias)(+GELU).
// 128x128 tile, BK=32, 4 waves. R13 analysis: single-buffer 2-barrier K-loop
// left GEMMs at ~315 TF aggregate — staging issued right before the barrier's
// vmcnt(0) drain exposed full memory latency per iter (same pathology R8
// found in attention; dbuf fixed it there). Two-phase manual unroll (K%64==0)
// pins buffer indices at compile time. 1 barrier per 32-K step. LDS 32KB.
// ---------------------------------------------------------------------------
template <typename TOUT, int EPI>
__global__ __launch_bounds__(256) void gemm_mfma(const bf16* __restrict__ A,
                                                 const bf16* __restrict__ Bt,
                                                 const float* __restrict__ bias,
                                                 TOUT* __restrict__ C,
                                                 int M, int N, int K) {
    __shared__ __align__(16) bf16 As[2][128 * 32];
    __shared__ __align__(16) bf16 Bs[2][128 * 32];
    const int tid = threadIdx.x;
    const int w = tid >> 6, lane = tid & 63;
    const int l = lane & 15, quad = lane >> 4;
    const int wm = w >> 1, wn = w & 1;
    const int m0 = blockIdx.x * 128, n0 = blockIdx.y * 128;

    const int r_in = lane >> 2;
    const int slot = lane & 3;
    const int rA0 = 2 * w * 16 + r_in, rA1 = rA0 + 16;
    const int q0 = slot ^ ((rA0 >> 1) & 3);
    const int q1 = slot ^ ((rA1 >> 1) & 3);
    const bf16* a0 = A + (size_t)(m0 + rA0) * K + q0 * 8;
    const bf16* a1 = A + (size_t)(m0 + rA1) * K + q1 * 8;
    const bf16* b0 = Bt + (size_t)(n0 + rA0) * K + q0 * 8;
    const bf16* b1 = Bt + (size_t)(n0 + rA1) * K + q1 * 8;
    const int lofs0 = 2 * w * 512;
    const int lofs1 = lofs0 + 512;

    const int swz = (quad ^ ((l >> 1) & 3)) * 8;
    f32x4 acc[4][4] = {};

    auto stage = [&](int k0, int buf) {
        GLD_LDS16(a0 + k0, &As[buf][lofs0]);
        GLD_LDS16(a1 + k0, &As[buf][lofs1]);
        GLD_LDS16(b0 + k0, &Bs[buf][lofs0]);
        GLD_LDS16(b1 + k0, &Bs[buf][lofs1]);
    };
    auto compute = [&](int buf) {
        short8 af[4], bfr[4];
#pragma unroll
        for (int mt = 0; mt < 4; mt++)
            af[mt] = *(const short8*)&As[buf][(wm * 64 + mt * 16 + l) * 32 + swz];
#pragma unroll
        for (int nt = 0; nt < 4; nt++)
            bfr[nt] = *(const short8*)&Bs[buf][(wn * 64 + nt * 16 + l) * 32 + swz];
#pragma unroll
        for (int mt = 0; mt < 4; mt++)
#pragma unroll
            for (int nt = 0; nt < 4; nt++)
                acc[mt][nt] = __builtin_amdgcn_mfma_f32_16x16x32_bf16(af[mt], bfr[nt], acc[mt][nt], 0, 0, 0);
    };

    stage(0, 0);
    for (int k0 = 0; k0 < K; k0 += 64) {
        __syncthreads();               // buf0 staged; prior buf1 reads done
        stage(k0 + 32, 1);             // K%64==0 => k0+32 < K always
        compute(0);
        __syncthreads();               // buf1 staged; prior buf0 reads done
        if (k0 + 64 < K) stage(k0 + 64, 0);
        compute(1);
    }

    float bs[4];
#pragma unroll
    for (int nt = 0; nt < 4; nt++)
        bs[nt] = bias ? bias[n0 + wn * 64 + nt * 16 + l] : 0.f;
#pragma unroll
    for (int mt = 0; mt < 4; mt++) {
#pragma unroll
        for (int nt = 0; nt < 4; nt++) {
            const int col = n0 + wn * 64 + nt * 16 + l;
#pragma unroll
            for (int r = 0; r < 4; r++) {
                const int row = m0 + wm * 64 + mt * 16 + quad * 4 + r;
                float val = acc[mt][nt][r] + bs[nt];
                if (EPI == 1) val = gelu_exact(val);
                C[(size_t)row * N + col] = from_f<TOUT>(val);
            }
        }
    }
}

// ---------------------------------------------------------------------------
// 64x64-tile MFMA GEMM (N=256 problems), double-buffered like gemm_mfma.
// ---------------------------------------------------------------------------
template <typename TOUT, int EPI>
__global__ __launch_bounds__(256) void gemm_mfma64(const bf16* __restrict__ A,
                                                   const bf16* __restrict__ Bt,
                                                   const float* __restrict__ bias,
                                                   TOUT* __restrict__ C,
                                                   int M, int N, int K) {
    __shared__ __align__(16) bf16 As[2][64 * 32];
    __shared__ __align__(16) bf16 Bs[2][64 * 32];
    const int tid = threadIdx.x;
    const int w = tid >> 6, lane = tid & 63;
    const int l = lane & 15, quad = lane >> 4;
    const int wm = w >> 1, wn = w & 1;
    const int m0 = blockIdx.x * 64, n0 = blockIdx.y * 64;

    const int srow = tid >> 2, slot = tid & 3;
    const int gq = slot ^ ((srow >> 1) & 3);
    const bf16* ag = A + (size_t)(m0 + srow) * K + gq * 8;
    const bf16* bg = Bt + (size_t)(n0 + srow) * K + gq * 8;
    const int lofs = w * 512;

    f32x4 acc[2][2] = {};

    auto stage = [&](int k0, int buf) {
        GLD_LDS16(ag + k0, &As[buf][lofs]);
        GLD_LDS16(bg + k0, &Bs[buf][lofs]);
    };
    auto compute = [&](int buf) {
        short8 af[2], bfr[2];
#pragma unroll
        for (int mt = 0; mt < 2; mt++) {
            const int row = wm * 32 + mt * 16 + l;
            af[mt] = *(const short8*)&As[buf][row * 32 + (quad ^ ((row >> 1) & 3)) * 8];
        }
#pragma unroll
        for (int nt = 0; nt < 2; nt++) {
            const int row = wn * 32 + nt * 16 + l;
            bfr[nt] = *(const short8*)&Bs[buf][row * 32 + (quad ^ ((row >> 1) & 3)) * 8];
        }
#pragma unroll
        for (int mt = 0; mt < 2; mt++)
#pragma unroll
            for (int nt = 0; nt < 2; nt++)
                acc[mt][nt] = __builtin_amdgcn_mfma_f32_16x16x32_bf16(af[mt], bfr[nt], acc[mt][nt], 0, 0, 0);
    };

    stage(0, 0);
    for (int k0 = 0; k0 < K; k0 += 64) {
        __syncthreads();
        stage(k0 + 32, 1);
        compute(0);
        __syncthreads();
        if (k0 + 64 < K) stage(k0 + 64, 0);
        compute(1);
    }

#pragma unroll
    for (int mt = 0; mt < 2; mt++) {
#pragma unroll
        for (int nt = 0; nt < 2; nt++) {
            const int col = n0 + wn * 32 + nt * 16 + l;
            const float bsv = bias ? bias[col] : 0.f;
#pragma unroll
            for (int r = 0; r < 4; r++) {
                const int row = m0 + wm * 32 + mt * 16 + quad * 4 + r;
                float val = acc[mt][nt][r] + bsv;
                if (EPI == 1) val = gelu_exact(val);
                C[(size_t)row * N + col] = from_f<TOUT>(val);
            }
        }
    }
}

// ---------------------------------------------------------------------------
// Transpose V per head: qkv [b][m][2304] (V at col 1536+h*64+e) -> vt [b][h][e][m]
// ---------------------------------------------------------------------------
__global__ __launch_bounds__(256) void transpose_v(const bf16* __restrict__ qkv,
                                                   bf16* __restrict__ vt) {
    __shared__ __align__(16) bf16 t[64][72];
    const int m0 = blockIdx.x * 64;
    const int h = blockIdx.y;
    const int tid = threadIdx.x;
    const int r = tid >> 2, c0 = (tid & 3) * 16;
    {
        const size_t g = (size_t)(m0 + r) * 2304 + 1536 + h * 64 + c0;
        *(short8*)&t[r][c0] = *(const short8*)(qkv + g);
        *(short8*)&t[r][c0 + 8] = *(const short8*)(qkv + g + 8);
    }
    __syncthreads();
    const int b = m0 >> 11, mm = m0 & 2047;
    const int e = tid >> 2, mi0 = (tid & 3) * 16;
    bf16 tmp[16];
#pragma unroll
    for (int j = 0; j < 16; j++) tmp[j] = t[mi0 + j][e];
    bf16* dst = vt + (((size_t)b * 12 + h) * 64 + e) * 2048 + mm + mi0;
    *(short8*)dst = *(short8*)&tmp[0];
    *(short8*)(dst + 8) = *(short8*)&tmp[8];
}

// ---------------------------------------------------------------------------
// MFMA flash attention (R10-proven config): 16x16x32 S^T, k-split x2,
// double-buffered staging, 256 thr = 4 waves, 128 q-rows/block.
// NOTE: (512,6) variant forced ~85-reg cap -> spills (R12). Keep (256,4).
// ---------------------------------------------------------------------------
__global__ __launch_bounds__(256, 4) void flash_attn_mfma(const bf16* __restrict__ qkv,
                                                          const bf16* __restrict__ vt,
                                                          const float* __restrict__ mask2,
                                                          bf16* __restrict__ opart0,
                                                          bf16* __restrict__ opart1,
                                                          float* __restrict__ lpart) {
    const int qt = blockIdx.x, h = blockIdx.y;
    const int b = blockIdx.z >> 1, kh = blockIdx.z & 1;
    const int tid = threadIdx.x;
    const int w = tid >> 6, lane = tid & 63;
    const int l = lane & 15, quad = lane >> 4;

    __shared__ __align__(16) bf16 Ks[2][64 * 64];
    __shared__ __align__(16) bf16 Vs[2][64 * 64];
    __shared__ __align__(16) bf16 Ps[4 * 16 * 64];   // 16 rows/wave

    short8 qf[2][2];
#pragma unroll
    for (int mt = 0; mt < 2; mt++) {
        const int qrow = qt * 128 + w * 32 + mt * 16 + l;
        const bf16* qp = qkv + ((size_t)b * 2048 + qrow) * 2304 + h * 64 + quad * 8;
        qf[mt][0] = *(const short8*)qp;
        qf[mt][1] = *(const short8*)(qp + 32);
    }

    short8 ones;
#pragma unroll
    for (int i = 0; i < 8; i++) ones[i] = (short)0x3F80;  // bf16 1.0

    f32x4 of[2][4] = {};
    f32x4 lacc[2] = {};
    bf16* Pw = Ps + w * 1024;

    const int kc0 = kh * 1024;
    int ldst[2];
    const bf16* kg[2];
    const bf16* vg[2];
#pragma unroll
    for (int i = 0; i < 2; i++) {
        const int cid = (w * 2 + i) * 64 + lane;
        const int row = cid >> 3, slot = cid & 7;
        const int gq = slot ^ (row & 7);
        ldst[i] = cid * 8;
        kg[i] = qkv + ((size_t)b * 2048 + kc0 + row) * 2304 + 768 + h * 64 + gq * 8;
        vg[i] = vt + (((size_t)b * 12 + h) * 64 + row) * 2048 + kc0 + gq * 8;
    }
    const float* mp = mask2 + (size_t)b * 2048 + kc0 + quad * 4;

    auto stage = [&](int buf) {
#pragma unroll
        for (int i = 0; i < 2; i++) {
            GLD_LDS16(kg[i], &Ks[buf][ldst[i]]);
            GLD_LDS16(vg[i], &Vs[buf][ldst[i]]);
            kg[i] += 64 * 2304;
            vg[i] += 64;
        }
    };

    int cur = 0;
    stage(0);

#pragma unroll 2
    for (int it = 0; it < 16; it++) {
        __syncthreads();
        float4 mrow[4];
#pragma unroll
        for (int nt = 0; nt < 4; nt++) mrow[nt] = *(const float4*)(mp + nt * 16);
        mp += 64;
        if (it < 15) stage(cur ^ 1);

        const bf16* Kc = Ks[cur];
        const bf16* Vc = Vs[cur];

        f32x4 st[2][4];
#pragma unroll
        for (int nt = 0; nt < 4; nt++) {
            const int rb = (nt * 16 + l) * 64;
            short8 kf0 = *(const short8*)&Kc[rb + ((quad) ^ (l & 7)) * 8];
            short8 kf1 = *(const short8*)&Kc[rb + ((4 + quad) ^ (l & 7)) * 8];
#pragma unroll
            for (int mt = 0; mt < 2; mt++) {
                f32x4 a = {mrow[nt].x, mrow[nt].y, mrow[nt].z, mrow[nt].w};
                a = __builtin_amdgcn_mfma_f32_16x16x32_bf16(kf0, qf[mt][0], a, 0, 0, 0);
                a = __builtin_amdgcn_mfma_f32_16x16x32_bf16(kf1, qf[mt][1], a, 0, 0, 0);
                st[mt][nt] = a;
            }
        }

        short8 pa[2][2];
#pragma unroll
        for (int mt = 0; mt < 2; mt++) {
#pragma unroll
            for (int nt = 0; nt < 4; nt++) {
                float p0 = exp2f(st[mt][nt][0]);
                float p1 = exp2f(st[mt][nt][1]);
                float p2 = exp2f(st[mt][nt][2]);
                float p3 = exp2f(st[mt][nt][3]);
                unsigned d0 = __builtin_amdgcn_perm(__builtin_bit_cast(unsigned, p1),
                                                    __builtin_bit_cast(unsigned, p0), 0x07060302u);
                unsigned d1 = __builtin_amdgcn_perm(__builtin_bit_cast(unsigned, p3),
                                                    __builtin_bit_cast(unsigned, p2), 0x07060302u);
                const int slot8 = (2 * nt + (quad >> 1)) ^ (l & 7);
                uint2 u = {d0, d1};
                *(uint2*)&Pw[l * 64 + slot8 * 8 + (quad & 1) * 4] = u;
            }
#pragma unroll
            for (int ks = 0; ks < 2; ks++)
                pa[mt][ks] = *(const short8*)&Pw[l * 64 + ((ks * 4 + quad) ^ (l & 7)) * 8];
        }

#pragma unroll
        for (int mt = 0; mt < 2; mt++) {
            lacc[mt] = __builtin_amdgcn_mfma_f32_16x16x32_bf16(pa[mt][0], ones, lacc[mt], 0, 0, 0);
            lacc[mt] = __builtin_amdgcn_mfma_f32_16x16x32_bf16(pa[mt][1], ones, lacc[mt], 0, 0, 0);
        }

#pragma unroll
        for (int nt = 0; nt < 4; nt++) {
            const int rb = (nt * 16 + l) * 64;
            short8 vf0 = *(const short8*)&Vc[rb + ((quad) ^ (l & 7)) * 8];
            short8 vf1 = *(const short8*)&Vc[rb + ((4 + quad) ^ (l & 7)) * 8];
#pragma unroll
            for (int mt = 0; mt < 2; mt++) {
                of[mt][nt] = __builtin_amdgcn_mfma_f32_16x16x32_bf16(pa[mt][0], vf0, of[mt][nt], 0, 0, 0);
                of[mt][nt] = __builtin_amdgcn_mfma_f32_16x16x32_bf16(pa[mt][1], vf1, of[mt][nt], 0, 0, 0);
            }
        }
        cur ^= 1;
    }

#pragma unroll
    for (int mt = 0; mt < 2; mt++) {
        if (l == 0) {
#pragma unroll
            for (int r = 0; r < 4; r++)
                lpart[(((size_t)kh * 4 + b) * 12 + h) * 2048 + qt * 128 + w * 32 + mt * 16 + quad * 4 + r] =
                    lacc[mt][r];
        }
    }

    bf16* op = kh ? opart1 : opart0;
#pragma unroll
    for (int mt = 0; mt < 2; mt++) {
#pragma unroll
        for (int r = 0; r < 4; r++) {
            const int row = qt * 128 + w * 32 + mt * 16 + quad * 4 + r;
#pragma unroll
            for (int nt = 0; nt < 4; nt++)
                op[((size_t)b * 2048 + row) * 768 + h * 64 + nt * 16 + l] =
                    from_f<bf16>(of[mt][nt][r]);
        }
    }
}

// ---------------------------------------------------------------------------
// Combine k-split partials: attn = (O0 + O1) / (l0 + l1). 4 elems/thread.
// ---------------------------------------------------------------------------
__global__ __launch_bounds__(256) void attn_combine(const bf16* __restrict__ o0,
                                                    const bf16* __restrict__ o1,
                                                    const float* __restrict__ lp,
                                                    bf16* __restrict__ outp) {
    const int t = blockIdx.x * 256 + threadIdx.x;
    const int col4 = t % 192;
    const int row = t / 192;
    const int b = row >> 11, m = row & 2047;
    const int h = col4 >> 4;
    const float l0 = lp[((size_t)b * 12 + h) * 2048 + m];
    const float l1 = lp[((size_t)(4 + b) * 12 + h) * 2048 + m];
    const float iv = 1.f / (l0 + l1);
    short4v a = ((const short4v*)o0)[t];
    short4v c = ((const short4v*)o1)[t];
    bf16 r[4];
#pragma unroll
    for (int i = 0; i < 4; i++) {
        float f = to_f(__builtin_bit_cast(bf16, a[i])) + to_f(__builtin_bit_cast(bf16, c[i]));
        r[i] = from_f<bf16>(f * iv);
    }
    ((short4v*)outp)[t] = *(short4v*)r;
}

// ---------------------------------------------------------------------------
// Row LayerNorm: out = LN(base + add) * gamma + beta.  D = 768, 256 thr/row.
// ---------------------------------------------------------------------------
template <typename TIN, typename TADD, typename TOUT>
__global__ __launch_bounds__(256) void ln_kernel(const TIN* __restrict__ base,
                                                 const TADD* __restrict__ add,
                                                 const float* __restrict__ gamma,
                                                 const float* __restrict__ beta,
                                                 TOUT* __restrict__ out) {
    const int row = blockIdx.x;
    const int tid = threadIdx.x;
    __shared__ float red[4];
    const size_t o = (size_t)row * 768;
    float v[3];
#pragma unroll
    for (int i = 0; i < 3; i++) {
        int d = tid + i * 256;
        v[i] = to_f(base[o + d]) + to_f(add[o + d]);
    }
    float s = v[0] + v[1] + v[2];
#pragma unroll
    for (int off = 32; off > 0; off >>= 1) s += __shfl_down(s, off, 64);
    const int wave = tid >> 6, lane = tid & 63;
    if (lane == 0) red[wave] = s;
    __syncthreads();
    float mu = (red[0] + red[1] + red[2] + red[3]) * (1.0f / 768.0f);
    float d0 = v[0] - mu, d1 = v[1] - mu, d2 = v[2] - mu;
    float sq = d0 * d0 + d1 * d1 + d2 * d2;
    __syncthreads();
#pragma unroll
    for (int off = 32; off > 0; off >>= 1) sq += __shfl_down(sq, off, 64);
    if (lane == 0) red[wave] = sq;
    __syncthreads();
    float var = (red[0] + red[1] + red[2] + red[3]) * (1.0f / 768.0f);
    float rs = rsqrtf(var + 1e-12f);
#pragma unroll
    for (int i = 0; i < 3; i++) {
        int d = tid + i * 256;
        float y = (v[i] - mu) * rs * gamma[d] + beta[d];
        out[o + d] = from_f<TOUT>(y);
    }
}

// ---------------------------------------------------------------------------
extern "C" void kernel_launch(void* const* d_in, const int* in_sizes, int n_in,
                              void* d_out, int out_size, void* d_ws, size_t ws_size,
                              hipStream_t stream) {
    const float* x    = (const float*)d_in[0];
    const float* mask = (const float*)d_in[1];
    const float* Pq = (const float*)d_in[2];
    const float* Vq = (const float*)d_in[3];
    const float* bq = (const float*)d_in[4];
    const float* Pk = (const float*)d_in[5];
    const float* Vk = (const float*)d_in[6];
    const float* bk = (const float*)d_in[7];
    const float* Pv = (const float*)d_in[8];
    const float* Vv = (const float*)d_in[9];
    const float* bv = (const float*)d_in[10];
    const float* Uo = (const float*)d_in[11];
    const float* Vo = (const float*)d_in[12];
    const float* bo = (const float*)d_in[13];
    const float* U1 = (const float*)d_in[14];
    const float* V1 = (const float*)d_in[15];
    const float* b1 = (const float*)d_in[16];
    const float* U2 = (const float*)d_in[17];
    const float* V2 = (const float*)d_in[18];
    const float* b2 = (const float*)d_in[19];
    const float* g1 = (const float*)d_in[20];
    const float* be1 = (const float*)d_in[21];
    const float* g2 = (const float*)d_in[22];
    const float* be2 = (const float*)d_in[23];

    // ---- workspace layout (bytes) ----
    char* p = (char*)d_ws;
    bf16* Wqkv_t = (bf16*)p;            p += (size_t)2304 * 768 * 2;
    bf16* Wo_t   = (bf16*)p;            p += (size_t)768 * 768 * 2;
    bf16* U1t    = (bf16*)p;            p += (size_t)256 * 768 * 2;
    bf16* V1t    = (bf16*)p;            p += (size_t)3072 * 256 * 2;
    bf16* U2t    = (bf16*)p;            p += (size_t)256 * 3072 * 2;
    bf16* V2t    = (bf16*)p;            p += (size_t)768 * 256 * 2;
    float* bias_qkv = (float*)p;        p += (size_t)2304 * 4;
    float* mask2 = (float*)p;           p += (size_t)8192 * 4;
    bf16* xb     = (bf16*)p;            // aliases x1b (xb dead after LN1)
    bf16* x1b    = xb;                  p += (size_t)8192 * 768 * 2;
    bf16* qkv    = (bf16*)p;            // gbuf aliases qkv+vt (dead after attn)
    bf16* gbuf   = qkv;                 p += (size_t)8192 * 2304 * 2;
    bf16* vtb    = (bf16*)p;            p += (size_t)8192 * 768 * 2;
    bf16* attnb  = (bf16*)p;            // t2 aliases attnb (dead after Wo GEMM)
    bf16* t2     = attnb;               p += (size_t)8192 * 768 * 2;
    char* regR   = p;                   p += (size_t)8192 * 768 * 4;  // 25.2 MB multi-use
    bf16* t1     = (bf16*)p;            p += (size_t)8192 * 256 * 2;
    // region R phases:
    bf16* Vot = (bf16*)regR;                       // prep only
    bf16* Uob = Vot + (size_t)768 * 256;           // prep only
    bf16* opart1 = (bf16*)regR;                    // attention partial (12.6MB)
    float* lpart = (float*)(regR + (size_t)8192 * 768 * 2);  // 786KB
    bf16* y1b = (bf16*)regR;                       // Wo-GEMM out (after combine)
    bf16* y2b = (bf16*)(regR + (size_t)8192 * 768 * 2);  // V2-GEMM out

    // 1) weight prep
    constexpr int N4_X = 8192 * 768 / 4;
    constexpr int N4_UO = 768 * 256 / 4;
    constexpr int CAST_BLOCKS = (N4_X + N4_UO + 255) / 256;  // 6336
    build_w_qkv_lds<<<dim3(6, 12, 3), 256, 0, stream>>>(Pq, Vq, Pk, Vk, Pv, Vv, Wqkv_t);
    cast_transpose_batch<<<2112, 256, 0, stream>>>(U1, V1, U2, V2, Vo, U1t, V1t, U2t, V2t, Vot);
    cast_f32_bf16_dual<<<CAST_BLOCKS, 256, 0, stream>>>(x, xb, N4_X, Uo, Uob, N4_UO);
    pack_bias_mask<<<35, 256, 0, stream>>>(bq, bk, bv, mask, bias_qkv, mask2);
    gemm_mfma<bf16, 0><<<dim3(6, 6), 256, 0, stream>>>(Vot, Uob, nullptr, Wo_t, 768, 768, 256);

    // 2) fused QKV GEMM
    gemm_mfma<bf16, 0><<<dim3(64, 18), 256, 0, stream>>>(xb, Wqkv_t, bias_qkv, qkv, 8192, 2304, 768);

    // 2.5) transpose V per head
    transpose_v<<<dim3(128, 12), 256, 0, stream>>>(qkv, vtb);

    // 3) flash attention, k-split x2 dbuf + combine
    flash_attn_mfma<<<dim3(16, 12, 8), 256, 0, stream>>>(qkv, vtb, mask2, attnb, opart1, lpart);
    attn_combine<<<6144, 256, 0, stream>>>(attnb, opart1, lpart, attnb);

    // 4) attn @ Wo + bo -> y1b bf16
    gemm_mfma<bf16, 0><<<dim3(64, 6), 256, 0, stream>>>(attnb, Wo_t, bo, y1b, 8192, 768, 768);

    // 5) x1 = LN1(xb + y1b) -> bf16
    ln_kernel<bf16, bf16, bf16><<<8192, 256, 0, stream>>>(xb, y1b, g1, be1, x1b);

    // 6) t1 = x1 @ U1
    gemm_mfma64<bf16, 0><<<dim3(128, 4), 256, 0, stream>>>(x1b, U1t, nullptr, t1, 8192, 256, 768);

    // 7) g = gelu(t1 @ V1 + b1) -> gbuf bf16
    gemm_mfma<bf16, 1><<<dim3(64, 24), 256, 0, stream>>>(t1, V1t, b1, gbuf, 8192, 3072, 256);

    // 8) t2 = g @ U2
    gemm_mfma64<bf16, 0><<<dim3(128, 4), 256, 0, stream>>>(gbuf, U2t, nullptr, t2, 8192, 256, 3072);

    // 9) y = t2 @ V2 + b2 -> y2b bf16
    gemm_mfma<bf16, 0><<<dim3(64, 6), 256, 0, stream>>>(t2, V2t, b2, y2b, 8192, 768, 256);

    // 10) out = LN2(x1 + y2b) -> f32
    ln_kernel<bf16, bf16, float><<<8192, 256, 0, stream>>>(x1b, y2b, g2, be2, (float*)d_out);
}